// Round 1
// 2012.574 us; speedup vs baseline: 1.0265x; 1.0265x over previous
//
#include <hip/hip_runtime.h>
#include <hip/hip_bf16.h>
#include <math.h>

typedef __hip_bfloat16 bf16;
typedef __attribute__((ext_vector_type(8))) short short8;
typedef __attribute__((ext_vector_type(4))) float f32x4;

#define S_LEN 1024
#define BATCH 4
#define M_ROWS 4096
#define DMODEL 1024
#define DFF 4096
#define NHEAD 8
#define DHEAD 128
#define WIN 100
#define LFWD 20

__device__ __forceinline__ void gl_lds16(const void* g, void* l) {
    __builtin_amdgcn_global_load_lds(
        (const __attribute__((address_space(1))) void*)g,
        (__attribute__((address_space(3))) void*)l, 16, 0, 0);
}

__device__ __forceinline__ float bf2f(unsigned short u) {
    return __uint_as_float(((unsigned)u) << 16);
}

// XCD-aware bijective swizzle (nb is always a multiple of 8 here):
// hardware flat ids round-robin XCDs, so give each XCD a contiguous chunk.
__device__ __forceinline__ int xcd_swz(int flat, int nb) {
    return (flat & 7) * (nb >> 3) + (flat >> 3);
}

// ---------------- MFMA GEMM (no split): C = act(A @ Bt^T + bias) ----------------
// 2-phase prefetch: stage tile t+1 into buf^1 while computing tile t.
template<typename TC>
__global__ __launch_bounds__(256)
void mfma_gemm(const bf16* __restrict__ A, const bf16* __restrict__ Bt,
               const float* __restrict__ bias, TC* __restrict__ C,
               int M, int N, int K, int act)
{
    __shared__ bf16 As[2][128 * 32];
    __shared__ bf16 Bs[2][128 * 32];
    const int gx = gridDim.x;
    const int nb = gx * gridDim.y;
    const int swz = xcd_swz(blockIdx.x + gx * blockIdx.y, nb);
    const int bn = (swz % gx) * 128;
    const int bm = (swz / gx) * 128;
    const int tid = threadIdx.x;
    const int w = tid >> 6, lane = tid & 63;
    const int wm = (w & 1) * 64, wn = (w >> 1) * 64;

    const int srow = w * 32 + (lane >> 2);
    const int selem = (lane & 3) * 8;
    const bf16* ga0 = A + (size_t)(bm + srow) * K + selem;
    const bf16* ga1 = ga0 + (size_t)16 * K;
    const bf16* gb0 = Bt + (size_t)(bn + srow) * K + selem;
    const bf16* gb1 = gb0 + (size_t)16 * K;
    const int l0 = (w * 32) * 32;
    const int l1 = (w * 32 + 16) * 32;

    f32x4 acc[4][4] = {};
    const int koff = (lane >> 4) * 8;
    const int fr = lane & 15;

    // prologue: stage tile 0
    gl_lds16(ga0, As[0] + l0); gl_lds16(ga1, As[0] + l1);
    gl_lds16(gb0, Bs[0] + l0); gl_lds16(gb1, Bs[0] + l1);
    ga0 += 32; ga1 += 32; gb0 += 32; gb1 += 32;
    __syncthreads();

    const int nk = K >> 5;
    int cur = 0;
    for (int t = 0; t < nk; ++t) {
        if (t + 1 < nk) {
            bf16* a = As[cur ^ 1]; bf16* b = Bs[cur ^ 1];
            gl_lds16(ga0, a + l0); gl_lds16(ga1, a + l1);
            gl_lds16(gb0, b + l0); gl_lds16(gb1, b + l1);
            ga0 += 32; ga1 += 32; gb0 += 32; gb1 += 32;
        }
        short8 af[4], bfr[4];
#pragma unroll
        for (int i = 0; i < 4; ++i)
            af[i] = *(const short8*)(As[cur] + (wm + i * 16 + fr) * 32 + koff);
#pragma unroll
        for (int j = 0; j < 4; ++j)
            bfr[j] = *(const short8*)(Bs[cur] + (wn + j * 16 + fr) * 32 + koff);
#pragma unroll
        for (int i = 0; i < 4; ++i)
#pragma unroll
            for (int j = 0; j < 4; ++j)
                acc[i][j] = __builtin_amdgcn_mfma_f32_16x16x32_bf16(
                    af[i], bfr[j], acc[i][j], 0, 0, 0);
        __syncthreads();   // drains vmcnt(0): prefetch issued ~a tile of compute ago
        cur ^= 1;
    }

    const int cq = lane >> 4, cn = lane & 15;
#pragma unroll
    for (int i = 0; i < 4; ++i) {
#pragma unroll
        for (int r = 0; r < 4; ++r) {
            int row = bm + wm + i * 16 + cq * 4 + r;
#pragma unroll
            for (int j = 0; j < 4; ++j) {
                int col = bn + wn + j * 16 + cn;
                float v = acc[i][j][r] + bias[col];
                if (act) v = v / (1.0f + __expf(-v));   // silu
                C[(size_t)row * N + col] = (TC)v;
            }
        }
    }
}

// ---------- MFMA GEMM split-K=2: z=0 -> C=acc+bias(+resid), z=1 -> P=acc ----------
// P is split: rows < prows0 go to P0, rest to P1 (both fp32, stride N).
__global__ __launch_bounds__(256)
void mfma_gemm_sk(const bf16* __restrict__ A, const bf16* __restrict__ Bt,
                  const float* __restrict__ bias, float* __restrict__ C,
                  const float* __restrict__ resid,
                  float* __restrict__ P0, float* __restrict__ P1, int prows0,
                  int M, int N, int K)
{
    __shared__ bf16 As[2][128 * 32];
    __shared__ bf16 Bs[2][128 * 32];
    const int gx = gridDim.x, gy = gridDim.y;
    const int nb = gx * gy * 2;
    const int swz = xcd_swz(blockIdx.x + gx * (blockIdx.y + gy * blockIdx.z), nb);
    const int bn = (swz % gx) * 128;
    const int bm = ((swz / gx) % gy) * 128;
    const int z  = swz / (gx * gy);
    const int khalf = K >> 1;
    const int kstart = z * khalf;
    const int tid = threadIdx.x;
    const int w = tid >> 6, lane = tid & 63;
    const int wm = (w & 1) * 64, wn = (w >> 1) * 64;

    const int srow = w * 32 + (lane >> 2);
    const int selem = (lane & 3) * 8;
    const bf16* ga0 = A + (size_t)(bm + srow) * K + kstart + selem;
    const bf16* ga1 = ga0 + (size_t)16 * K;
    const bf16* gb0 = Bt + (size_t)(bn + srow) * K + kstart + selem;
    const bf16* gb1 = gb0 + (size_t)16 * K;
    const int l0 = (w * 32) * 32;
    const int l1 = (w * 32 + 16) * 32;

    f32x4 acc[4][4] = {};
    const int koff = (lane >> 4) * 8;
    const int fr = lane & 15;

    gl_lds16(ga0, As[0] + l0); gl_lds16(ga1, As[0] + l1);
    gl_lds16(gb0, Bs[0] + l0); gl_lds16(gb1, Bs[0] + l1);
    ga0 += 32; ga1 += 32; gb0 += 32; gb1 += 32;
    __syncthreads();

    const int nk = khalf >> 5;
    int cur = 0;
    for (int t = 0; t < nk; ++t) {
        if (t + 1 < nk) {
            bf16* a = As[cur ^ 1]; bf16* b = Bs[cur ^ 1];
            gl_lds16(ga0, a + l0); gl_lds16(ga1, a + l1);
            gl_lds16(gb0, b + l0); gl_lds16(gb1, b + l1);
            ga0 += 32; ga1 += 32; gb0 += 32; gb1 += 32;
        }
        short8 af[4], bfr[4];
#pragma unroll
        for (int i = 0; i < 4; ++i)
            af[i] = *(const short8*)(As[cur] + (wm + i * 16 + fr) * 32 + koff);
#pragma unroll
        for (int j = 0; j < 4; ++j)
            bfr[j] = *(const short8*)(Bs[cur] + (wn + j * 16 + fr) * 32 + koff);
#pragma unroll
        for (int i = 0; i < 4; ++i)
#pragma unroll
            for (int j = 0; j < 4; ++j)
                acc[i][j] = __builtin_amdgcn_mfma_f32_16x16x32_bf16(
                    af[i], bfr[j], acc[i][j], 0, 0, 0);
        __syncthreads();
        cur ^= 1;
    }

    const int cq = lane >> 4, cn = lane & 15;
#pragma unroll
    for (int i = 0; i < 4; ++i) {
#pragma unroll
        for (int r = 0; r < 4; ++r) {
            int row = bm + wm + i * 16 + cq * 4 + r;
#pragma unroll
            for (int j = 0; j < 4; ++j) {
                int col = bn + wn + j * 16 + cn;
                float v = acc[i][j][r];
                if (z == 0) {
                    v += bias[col];
                    if (resid) v += resid[(size_t)row * N + col];
                    C[(size_t)row * N + col] = v;
                } else {
                    float* P = (row < prows0) ? (P0 + (size_t)row * N + col)
                                              : (P1 + (size_t)(row - prows0) * N + col);
                    *P = v;
                }
            }
        }
    }
}

// -------- transpose+cast: W (K x N fp32, row stride ld) -> Wt (N x K bf16) --------
__global__ void transpose_kernel(const float* __restrict__ W, bf16* __restrict__ Wt,
                                 int K, int N, int ld)
{
    __shared__ float t[32][33];
    const int n0 = blockIdx.x * 32, k0 = blockIdx.y * 32;
    const int tx = threadIdx.x & 31, ty = threadIdx.x >> 5;
#pragma unroll
    for (int i = 0; i < 32; i += 8)
        t[ty + i][tx] = W[(size_t)(k0 + ty + i) * ld + n0 + tx];
    __syncthreads();
#pragma unroll
    for (int i = 0; i < 32; i += 8)
        Wt[(size_t)(n0 + ty + i) * K + k0 + tx] = (bf16)t[tx][ty + i];
}

// ---------------- fp32 -> bf16 convert ----------------
__global__ void cvt_kernel(const float* __restrict__ s, bf16* __restrict__ d)
{
    size_t i = ((size_t)blockIdx.x * 256 + threadIdx.x) * 4;
    float4 v = *(const float4*)(s + i);
    d[i] = (bf16)v.x; d[i + 1] = (bf16)v.y; d[i + 2] = (bf16)v.z; d[i + 3] = (bf16)v.w;
}

// ---------------- concat 3 bias vectors of 1024 fp32 ----------------
__global__ void concat3_kernel(const float* __restrict__ a, const float* __restrict__ b,
                               const float* __restrict__ c, float* __restrict__ o)
{
    int i = blockIdx.x * 256 + threadIdx.x;   // 0..3071
    o[i] = (i < 1024) ? a[i] : (i < 2048 ? b[i - 1024] : c[i - 2048]);
}

// ---------------- h = pad ? 0 : h + P ----------------
__global__ void pad_red_kernel(float* __restrict__ h, const float* __restrict__ P,
                               const int* __restrict__ xlen)
{
    int row = blockIdx.x;
    int b = row >> 10, s = row & 1023;
    int len = xlen[b] >> 2;
    size_t off = (size_t)row * DMODEL;
    if (s >= len) {
        for (int d = threadIdx.x; d < DMODEL; d += 256) h[off + d] = 0.0f;
    } else {
        for (int d = threadIdx.x; d < DMODEL; d += 256) h[off + d] += P[off + d];
    }
}

// ---------------- h += P (split P0/P1) ----------------
__global__ void reduce2_kernel(float* __restrict__ h, const float* __restrict__ P0,
                               const float* __restrict__ P1, int prows0)
{
    int row = blockIdx.x;
    const float* P = (row < prows0) ? (P0 + (size_t)row * DMODEL)
                                    : (P1 + (size_t)(row - prows0) * DMODEL);
    size_t off = (size_t)row * DMODEL;
#pragma unroll
    for (int t = 0; t < 4; ++t) {
        int d = threadIdx.x + 256 * t;
        h[off + d] += P[d];
    }
}

// ---------------- LayerNorm (row of 1024), fp32 in, TO out; optional P fold ------
template<typename TO, bool RED>
__global__ void ln_kernel(float* __restrict__ x, const float* __restrict__ P0,
                          const float* __restrict__ sc, const float* __restrict__ bi,
                          TO* __restrict__ y)
{
    int row = blockIdx.x;
    float* xr = x + (size_t)row * DMODEL;
    const float* pr = RED ? (P0 + (size_t)row * DMODEL) : nullptr;
    float vals[4];
    float lsum = 0.0f, lsq = 0.0f;
#pragma unroll
    for (int t = 0; t < 4; ++t) {
        int d = threadIdx.x + 256 * t;
        float v = xr[d];
        if (RED) { v += pr[d]; xr[d] = v; }
        vals[t] = v; lsum += v; lsq += v * v;
    }
    for (int o = 32; o > 0; o >>= 1) {
        lsum += __shfl_down(lsum, o, 64);
        lsq  += __shfl_down(lsq,  o, 64);
    }
    __shared__ float s1[4], s2[4];
    int wv = threadIdx.x >> 6, ln = threadIdx.x & 63;
    if (ln == 0) { s1[wv] = lsum; s2[wv] = lsq; }
    __syncthreads();
    if (threadIdx.x == 0) {
        float a = s1[0] + s1[1] + s1[2] + s1[3];
        float b = s2[0] + s2[1] + s2[2] + s2[3];
        float mu = a * (1.0f / DMODEL);
        float var = b * (1.0f / DMODEL) - mu * mu;
        s1[0] = mu;
        s2[0] = rsqrtf(fmaxf(var, 0.0f) + 1e-5f);
    }
    __syncthreads();
    float mu = s1[0], inv = s2[0];
#pragma unroll
    for (int t = 0; t < 4; ++t) {
        int d = threadIdx.x + 256 * t;
        y[(size_t)row * DMODEL + d] = (TO)((vals[t] - mu) * inv * sc[d] + bi[d]);
    }
}

// ---------------- RoPE (in-place, bf16, strided) ----------------
__global__ void rope_kernel(bf16* __restrict__ q, bf16* __restrict__ k, int stride)
{
    size_t idx = (size_t)blockIdx.x * 256 + threadIdx.x;
    int d = idx & 63;
    size_t rest = idx >> 6;
    int hh = rest & 7;
    int s = (rest >> 3) & 1023;
    size_t base = (rest >> 3) * stride + (size_t)hh * DHEAD;
    // 10000^(-d/64) = 2^(-d * log2(10000)/64); v_exp_f32 is single-instruction
    float inv = exp2f((float)d * -0.20762050593045235f);
    float ang = (float)s * inv;
    float c, si;
    __sincosf(ang, &si, &c);
    {
        float x1 = (float)q[base + d], x2 = (float)q[base + 64 + d];
        q[base + d]      = (bf16)(x1 * c - x2 * si);
        q[base + 64 + d] = (bf16)(x1 * si + x2 * c);
    }
    {
        float x1 = (float)k[base + d], x2 = (float)k[base + 64 + d];
        k[base + d]      = (bf16)(x1 * c - x2 * si);
        k[base + 64 + d] = (bf16)(x1 * si + x2 * c);
    }
}

// ---------------- mean of v over all s, per (b,h) ----------------
__global__ void vmean_kernel(const bf16* __restrict__ v, float* __restrict__ vmean,
                             int stride)
{
    int bh = blockIdx.x;
    int b = bh >> 3, hh = bh & 7;
    int d = threadIdx.x;  // 128
    float acc = 0.0f;
    for (int s = 0; s < S_LEN; ++s)
        acc += (float)v[((size_t)(b * S_LEN + s)) * stride + hh * DHEAD + d];
    vmean[(size_t)bh * DHEAD + d] = acc * (1.0f / S_LEN);
}

// ---------------- windowed attention, one wave per (b,h,i) ----------------
__global__ void attn_kernel(const bf16* __restrict__ q, const bf16* __restrict__ k,
                            const bf16* __restrict__ v, const float* __restrict__ vmean,
                            const int* __restrict__ xlen, bf16* __restrict__ ctx,
                            int stride)
{
    const int lane = threadIdx.x;  // 64
    int bhi = blockIdx.x;
    int i = bhi & 1023;
    int hh = (bhi >> 10) & 7;
    int b = bhi >> 13;
    int len = xlen[b] >> 2;
    size_t rowQ = ((size_t)(b * S_LEN + i)) * stride + hh * DHEAD;
    size_t rowC = ((size_t)(b * S_LEN + i)) * DMODEL + hh * DHEAD;
    int j0 = i - (WIN - 1); if (j0 < 0) j0 = 0;
    if (j0 >= len) {
        const float* vm = vmean + (size_t)(b * NHEAD + hh) * DHEAD;
        ctx[rowC + 2 * lane]     = (bf16)vm[2 * lane];
        ctx[rowC + 2 * lane + 1] = (bf16)vm[2 * lane + 1];
        return;
    }
    int j1 = i + LFWD; if (j1 > S_LEN - 1) j1 = S_LEN - 1;
    if (j1 > len - 1) j1 = len - 1;

    __shared__ float qs[DHEAD];
    __shared__ float p[128];
    qs[lane]      = (float)q[rowQ + lane];
    qs[lane + 64] = (float)q[rowQ + 64 + lane];
    __syncthreads();

    const float scale = 0.088388347648318447f;  // 1/sqrt(128)
    int jA = j0 + lane, jB = j0 + 64 + lane;
    float s0 = -1e30f, s1 = -1e30f;
    if (jA <= j1) {
        const short8* kr = (const short8*)(k + ((size_t)(b * S_LEN + jA)) * stride + hh * DHEAD);
        float acc = 0.0f;
#pragma unroll
        for (int c = 0; c < 16; ++c) {
            short8 kk = kr[c];
#pragma unroll
            for (int t = 0; t < 8; ++t)
                acc += qs[c * 8 + t] * bf2f((unsigned short)kk[t]);
        }
        s0 = acc * scale;
    }
    if (jB <= j1) {
        const short8* kr = (const short8*)(k + ((size_t)(b * S_LEN + jB)) * stride + hh * DHEAD);
        float acc = 0.0f;
#pragma unroll
        for (int c = 0; c < 16; ++c) {
            short8 kk = kr[c];
#pragma unroll
            for (int t = 0; t < 8; ++t)
                acc += qs[c * 8 + t] * bf2f((unsigned short)kk[t]);
        }
        s1 = acc * scale;
    }
    float m = fmaxf(s0, s1);
    for (int o = 32; o > 0; o >>= 1) m = fmaxf(m, __shfl_down(m, o, 64));
    m = __shfl(m, 0, 64);
    float e0 = (jA <= j1) ? __expf(s0 - m) : 0.0f;
    float e1 = (jB <= j1) ? __expf(s1 - m) : 0.0f;
    float ssum = e0 + e1;
    for (int o = 32; o > 0; o >>= 1) ssum += __shfl_down(ssum, o, 64);
    ssum = __shfl(ssum, 0, 64);
    float inv = 1.0f / fmaxf(ssum, 1e-30f);
    p[lane] = e0 * inv;
    p[lane + 64] = e1 * inv;
    __syncthreads();

    float a0 = 0.0f, a1 = 0.0f;
    for (int j = j0; j <= j1; ++j) {
        float pj = p[j - j0];
        const unsigned* vr = (const unsigned*)(v + ((size_t)(b * S_LEN + j)) * stride + hh * DHEAD);
        unsigned u = vr[lane];
        a0 += pj * bf2f((unsigned short)(u & 0xffff));
        a1 += pj * bf2f((unsigned short)(u >> 16));
    }
    ctx[rowC + 2 * lane]     = (bf16)a0;
    ctx[rowC + 2 * lane + 1] = (bf16)a1;
}

extern "C" void kernel_launch(void* const* d_in, const int* in_sizes, int n_in,
                              void* d_out, int out_size, void* d_ws, size_t ws_size,
                              hipStream_t stream)
{
    const float* x      = (const float*)d_in[0];
    const int*   xlen   = (const int*)d_in[1];
    const float* Wp     = (const float*)d_in[2];
    const float* bp     = (const float*)d_in[3];
    const float* ln1_s  = (const float*)d_in[4];
    const float* ln1_b  = (const float*)d_in[5];
    const float* Wq     = (const float*)d_in[6];
    const float* bq     = (const float*)d_in[7];
    const float* Wk     = (const float*)d_in[8];
    const float* bk     = (const float*)d_in[9];
    const float* Wv     = (const float*)d_in[10];
    const float* bv     = (const float*)d_in[11];
    const float* Wo     = (const float*)d_in[12];
    const float* bo     = (const float*)d_in[13];
    const float* ln2_s  = (const float*)d_in[14];
    const float* ln2_b  = (const float*)d_in[15];
    const float* W1     = (const float*)d_in[16];
    const float* b1     = (const float*)d_in[17];
    const float* W2     = (const float*)d_in[18];
    const float* b2     = (const float*)d_in[19];
    const float* lnf_s  = (const float*)d_in[20];
    const float* lnf_b  = (const float*)d_in[21];
    (void)in_sizes; (void)n_in; (void)out_size; (void)ws_size;

    // ---- workspace: 56 MB + ~28 KB ----
    const size_t MD = (size_t)M_ROWS * DMODEL;            // 4M elems
    float* h     = (float*)d_ws;                          // [0,16) MB
    bf16*  y     = (bf16*)(h + MD);                       // [16,24) MB (LN out / ctx)
    float* yfP   = (float*)(h + MD);                      // same region as fp32 (8 MB)
    bf16*  U     = y + MD;                                // [24,56) MB union
    bf16*  xb    = U;                                     // 16 MB (proj input)
    bf16*  qkv   = U;                                     // 24 MB, stride 3072
    bf16*  mid   = U;                                     // 32 MB (FFN mid)
    float* UfP   = (float*)U;                             // U as fp32 partial (16 MB)
    float* UfP2  = (float*)(U + 8 * 1024 * 1024);         // U second half fp32
    float* vmean = (float*)(U + 16 * 1024 * 1024);        // ws+56 MB, 16 KB
    float* bqkv  = vmean + BATCH * NHEAD * DHEAD;         // 12 KB
    // d_out (16 MB fp32) is scratch until final LN:
    bf16*  wt    = (bf16*)d_out;                          // [0,8) MB: weight^T
    float* doP   = (float*)((char*)d_out + 8 * 1024 * 1024); // [8,16) MB fp32 partial

    const int QS = 3 * DMODEL;   // qkv row stride

    dim3 blk(256);
    dim3 gSK(DMODEL / 128, M_ROWS / 128, 2);              // split-K grid, 512 blocks

    // xb = bf16(x); h = xb @ Wp^T + bp (split-K, P in U upper half); pad+reduce
    cvt_kernel<<<(2 * MD) / (256 * 4), blk, 0, stream>>>(x, xb);
    transpose_kernel<<<dim3(DMODEL / 32, 2048 / 32), blk, 0, stream>>>(Wp, wt, 2048, DMODEL, DMODEL);
    mfma_gemm_sk<<<gSK, blk, 0, stream>>>(xb, wt, bp, h, nullptr,
                                          UfP2, nullptr, M_ROWS, M_ROWS, DMODEL, 2048);
    pad_red_kernel<<<M_ROWS, blk, 0, stream>>>(h, UfP2, xlen);

    for (int l = 0; l < 4; ++l) {
        const size_t wD  = (size_t)l * DMODEL * DMODEL;
        const size_t wF  = (size_t)l * DMODEL * DFF;   // W1 (1024 x 4096)
        const size_t wF2 = (size_t)l * DFF * DMODEL;   // W2 (4096 x 1024)
        const size_t vD  = (size_t)l * DMODEL;
        const size_t vF  = (size_t)l * DFF;

        ln_kernel<bf16, false><<<M_ROWS, blk, 0, stream>>>(h, nullptr,
                                                           ln1_s + vD, ln1_b + vD, y);

        // fused QKV (768 blocks, no split)
        transpose_kernel<<<dim3(32, 32), blk, 0, stream>>>(Wq + wD, wt, DMODEL, DMODEL, DMODEL);
        transpose_kernel<<<dim3(32, 32), blk, 0, stream>>>(Wk + wD, wt + MD / 4, DMODEL, DMODEL, DMODEL);
        transpose_kernel<<<dim3(32, 32), blk, 0, stream>>>(Wv + wD, wt + MD / 2, DMODEL, DMODEL, DMODEL);
        concat3_kernel<<<12, blk, 0, stream>>>(bq + vD, bk + vD, bv + vD, bqkv);
        mfma_gemm<bf16><<<dim3(3 * DMODEL / 128, M_ROWS / 128), blk, 0, stream>>>(
            y, wt, bqkv, qkv, M_ROWS, 3 * DMODEL, DMODEL, 0);

        bf16* qb = qkv;
        bf16* kb = qkv + DMODEL;
        bf16* vb = qkv + 2 * DMODEL;
        rope_kernel<<<(M_ROWS * NHEAD * 64) / 256, blk, 0, stream>>>(qb, kb, QS);
        vmean_kernel<<<BATCH * NHEAD, dim3(DHEAD), 0, stream>>>(vb, vmean, QS);
        attn_kernel<<<BATCH * NHEAD * S_LEN, dim3(64), 0, stream>>>(qb, kb, vb, vmean,
                                                                    xlen, y, QS);

        // h = h + ctx @ Wo^T + bo  (split-K; P in U[0:16) — qkv dead)
        transpose_kernel<<<dim3(32, 32), blk, 0, stream>>>(Wo + wD, wt, DMODEL, DMODEL, DMODEL);
        mfma_gemm_sk<<<gSK, blk, 0, stream>>>(y, wt, bo + vD, h, h,
                                              UfP, nullptr, M_ROWS, M_ROWS, DMODEL, 1024);

        // ln2 fused with Wo's partial reduce: h += P; y = LN(h)
        ln_kernel<bf16, true><<<M_ROWS, blk, 0, stream>>>(h, UfP,
                                                          ln2_s + vD, ln2_b + vD, y);

        // FFN1 full width: mid = silu(y @ W1^T + b1)   (1024 blocks)
        transpose_kernel<<<dim3(DFF / 32, DMODEL / 32), blk, 0, stream>>>(
            W1 + wF, wt, DMODEL, DFF, DFF);
        mfma_gemm<bf16><<<dim3(DFF / 128, M_ROWS / 128), blk, 0, stream>>>(
            y, wt, b1 + vF, mid, M_ROWS, DFF, DMODEL, 1);

        // FFN2 split-K: h = h + mid @ W2^T + b2; P split: rows<2048 -> y-region,
        // rest -> d_out[8:16)  (y dead after FFN1; both regions free)
        transpose_kernel<<<dim3(DMODEL / 32, DFF / 32), blk, 0, stream>>>(
            W2 + wF2, wt, DFF, DMODEL, DMODEL);
        mfma_gemm_sk<<<gSK, blk, 0, stream>>>(mid, wt, b2 + vD, h, h,
                                              yfP, doP, 2048, M_ROWS, DMODEL, DFF);
        reduce2_kernel<<<M_ROWS, blk, 0, stream>>>(h, yfP, doP, 2048);
    }

    ln_kernel<float, false><<<M_ROWS, blk, 0, stream>>>(h, nullptr, lnf_s, lnf_b,
                                                        (float*)d_out);
}

// Round 2
// 1697.577 us; speedup vs baseline: 1.2170x; 1.1856x over previous
//
#include <hip/hip_runtime.h>
#include <hip/hip_bf16.h>
#include <math.h>

typedef __hip_bfloat16 bf16;
typedef __attribute__((ext_vector_type(8))) short short8;
typedef __attribute__((ext_vector_type(4))) float f32x4;

#define S_LEN 1024
#define BATCH 4
#define M_ROWS 4096
#define DMODEL 1024
#define DFF 4096
#define NHEAD 8
#define DHEAD 128
#define WIN 100
#define LFWD 20

__device__ __forceinline__ void gl_lds16(const void* g, void* l) {
    __builtin_amdgcn_global_load_lds(
        (const __attribute__((address_space(1))) void*)g,
        (__attribute__((address_space(3))) void*)l, 16, 0, 0);
}

__device__ __forceinline__ float bf2f(unsigned short u) {
    return __uint_as_float(((unsigned)u) << 16);
}

// XCD-aware bijective swizzle (nb is always a multiple of 8 here):
// hardware flat ids round-robin XCDs, so give each XCD a contiguous chunk.
__device__ __forceinline__ int xcd_swz(int flat, int nb) {
    return (flat & 7) * (nb >> 3) + (flat >> 3);
}

// ---------------- MFMA GEMM (no split): C = act(A @ Bt^T + bias) ----------------
// 2-phase prefetch: stage tile t+1 into buf^1 while computing tile t.
template<typename TC>
__global__ __launch_bounds__(256)
void mfma_gemm(const bf16* __restrict__ A, const bf16* __restrict__ Bt,
               const float* __restrict__ bias, TC* __restrict__ C,
               int M, int N, int K, int act)
{
    __shared__ bf16 As[2][128 * 32];
    __shared__ bf16 Bs[2][128 * 32];
    const int gx = gridDim.x;
    const int nb = gx * gridDim.y;
    const int swz = xcd_swz(blockIdx.x + gx * blockIdx.y, nb);
    const int bn = (swz % gx) * 128;
    const int bm = (swz / gx) * 128;
    const int tid = threadIdx.x;
    const int w = tid >> 6, lane = tid & 63;
    const int wm = (w & 1) * 64, wn = (w >> 1) * 64;

    const int srow = w * 32 + (lane >> 2);
    const int selem = (lane & 3) * 8;
    const bf16* ga0 = A + (size_t)(bm + srow) * K + selem;
    const bf16* ga1 = ga0 + (size_t)16 * K;
    const bf16* gb0 = Bt + (size_t)(bn + srow) * K + selem;
    const bf16* gb1 = gb0 + (size_t)16 * K;
    const int l0 = (w * 32) * 32;
    const int l1 = (w * 32 + 16) * 32;

    f32x4 acc[4][4] = {};
    const int koff = (lane >> 4) * 8;
    const int fr = lane & 15;

    // prologue: stage tile 0
    gl_lds16(ga0, As[0] + l0); gl_lds16(ga1, As[0] + l1);
    gl_lds16(gb0, Bs[0] + l0); gl_lds16(gb1, Bs[0] + l1);
    ga0 += 32; ga1 += 32; gb0 += 32; gb1 += 32;
    __syncthreads();

    const int nk = K >> 5;
    int cur = 0;
    for (int t = 0; t < nk; ++t) {
        if (t + 1 < nk) {
            bf16* a = As[cur ^ 1]; bf16* b = Bs[cur ^ 1];
            gl_lds16(ga0, a + l0); gl_lds16(ga1, a + l1);
            gl_lds16(gb0, b + l0); gl_lds16(gb1, b + l1);
            ga0 += 32; ga1 += 32; gb0 += 32; gb1 += 32;
        }
        short8 af[4], bfr[4];
#pragma unroll
        for (int i = 0; i < 4; ++i)
            af[i] = *(const short8*)(As[cur] + (wm + i * 16 + fr) * 32 + koff);
#pragma unroll
        for (int j = 0; j < 4; ++j)
            bfr[j] = *(const short8*)(Bs[cur] + (wn + j * 16 + fr) * 32 + koff);
#pragma unroll
        for (int i = 0; i < 4; ++i)
#pragma unroll
            for (int j = 0; j < 4; ++j)
                acc[i][j] = __builtin_amdgcn_mfma_f32_16x16x32_bf16(
                    af[i], bfr[j], acc[i][j], 0, 0, 0);
        __syncthreads();   // drains vmcnt(0): prefetch issued ~a tile of compute ago
        cur ^= 1;
    }

    const int cq = lane >> 4, cn = lane & 15;
#pragma unroll
    for (int i = 0; i < 4; ++i) {
#pragma unroll
        for (int r = 0; r < 4; ++r) {
            int row = bm + wm + i * 16 + cq * 4 + r;
#pragma unroll
            for (int j = 0; j < 4; ++j) {
                int col = bn + wn + j * 16 + cn;
                float v = acc[i][j][r] + bias[col];
                if (act) v = v / (1.0f + __expf(-v));   // silu
                C[(size_t)row * N + col] = (TC)v;
            }
        }
    }
}

// ---------- MFMA GEMM split-K=2: z=0 -> C=acc+bias(+resid), z=1 -> P=acc ----------
// P is split: rows < prows0 go to P0, rest to P1 (both fp32, stride N).
__global__ __launch_bounds__(256)
void mfma_gemm_sk(const bf16* __restrict__ A, const bf16* __restrict__ Bt,
                  const float* __restrict__ bias, float* __restrict__ C,
                  const float* __restrict__ resid,
                  float* __restrict__ P0, float* __restrict__ P1, int prows0,
                  int M, int N, int K)
{
    __shared__ bf16 As[2][128 * 32];
    __shared__ bf16 Bs[2][128 * 32];
    const int gx = gridDim.x, gy = gridDim.y;
    const int nb = gx * gy * 2;
    const int swz = xcd_swz(blockIdx.x + gx * (blockIdx.y + gy * blockIdx.z), nb);
    const int bn = (swz % gx) * 128;
    const int bm = ((swz / gx) % gy) * 128;
    const int z  = swz / (gx * gy);
    const int khalf = K >> 1;
    const int kstart = z * khalf;
    const int tid = threadIdx.x;
    const int w = tid >> 6, lane = tid & 63;
    const int wm = (w & 1) * 64, wn = (w >> 1) * 64;

    const int srow = w * 32 + (lane >> 2);
    const int selem = (lane & 3) * 8;
    const bf16* ga0 = A + (size_t)(bm + srow) * K + kstart + selem;
    const bf16* ga1 = ga0 + (size_t)16 * K;
    const bf16* gb0 = Bt + (size_t)(bn + srow) * K + kstart + selem;
    const bf16* gb1 = gb0 + (size_t)16 * K;
    const int l0 = (w * 32) * 32;
    const int l1 = (w * 32 + 16) * 32;

    f32x4 acc[4][4] = {};
    const int koff = (lane >> 4) * 8;
    const int fr = lane & 15;

    gl_lds16(ga0, As[0] + l0); gl_lds16(ga1, As[0] + l1);
    gl_lds16(gb0, Bs[0] + l0); gl_lds16(gb1, Bs[0] + l1);
    ga0 += 32; ga1 += 32; gb0 += 32; gb1 += 32;
    __syncthreads();

    const int nk = khalf >> 5;
    int cur = 0;
    for (int t = 0; t < nk; ++t) {
        if (t + 1 < nk) {
            bf16* a = As[cur ^ 1]; bf16* b = Bs[cur ^ 1];
            gl_lds16(ga0, a + l0); gl_lds16(ga1, a + l1);
            gl_lds16(gb0, b + l0); gl_lds16(gb1, b + l1);
            ga0 += 32; ga1 += 32; gb0 += 32; gb1 += 32;
        }
        short8 af[4], bfr[4];
#pragma unroll
        for (int i = 0; i < 4; ++i)
            af[i] = *(const short8*)(As[cur] + (wm + i * 16 + fr) * 32 + koff);
#pragma unroll
        for (int j = 0; j < 4; ++j)
            bfr[j] = *(const short8*)(Bs[cur] + (wn + j * 16 + fr) * 32 + koff);
#pragma unroll
        for (int i = 0; i < 4; ++i)
#pragma unroll
            for (int j = 0; j < 4; ++j)
                acc[i][j] = __builtin_amdgcn_mfma_f32_16x16x32_bf16(
                    af[i], bfr[j], acc[i][j], 0, 0, 0);
        __syncthreads();
        cur ^= 1;
    }

    const int cq = lane >> 4, cn = lane & 15;
#pragma unroll
    for (int i = 0; i < 4; ++i) {
#pragma unroll
        for (int r = 0; r < 4; ++r) {
            int row = bm + wm + i * 16 + cq * 4 + r;
#pragma unroll
            for (int j = 0; j < 4; ++j) {
                int col = bn + wn + j * 16 + cn;
                float v = acc[i][j][r];
                if (z == 0) {
                    v += bias[col];
                    if (resid) v += resid[(size_t)row * N + col];
                    C[(size_t)row * N + col] = v;
                } else {
                    float* P = (row < prows0) ? (P0 + (size_t)row * N + col)
                                              : (P1 + (size_t)(row - prows0) * N + col);
                    *P = v;
                }
            }
        }
    }
}

// -------- transpose+cast: W (K x N fp32, row stride ld) -> Wt (N x K bf16) --------
__global__ void transpose_kernel(const float* __restrict__ W, bf16* __restrict__ Wt,
                                 int K, int N, int ld)
{
    __shared__ float t[32][33];
    const int n0 = blockIdx.x * 32, k0 = blockIdx.y * 32;
    const int tx = threadIdx.x & 31, ty = threadIdx.x >> 5;
#pragma unroll
    for (int i = 0; i < 32; i += 8)
        t[ty + i][tx] = W[(size_t)(k0 + ty + i) * ld + n0 + tx];
    __syncthreads();
#pragma unroll
    for (int i = 0; i < 32; i += 8)
        Wt[(size_t)(n0 + ty + i) * K + k0 + tx] = (bf16)t[tx][ty + i];
}

// ---------------- fp32 -> bf16 convert ----------------
__global__ void cvt_kernel(const float* __restrict__ s, bf16* __restrict__ d)
{
    size_t i = ((size_t)blockIdx.x * 256 + threadIdx.x) * 4;
    float4 v = *(const float4*)(s + i);
    d[i] = (bf16)v.x; d[i + 1] = (bf16)v.y; d[i + 2] = (bf16)v.z; d[i + 3] = (bf16)v.w;
}

// ---------------- concat 3 bias vectors of 1024 fp32 ----------------
__global__ void concat3_kernel(const float* __restrict__ a, const float* __restrict__ b,
                               const float* __restrict__ c, float* __restrict__ o)
{
    int i = blockIdx.x * 256 + threadIdx.x;   // 0..3071
    o[i] = (i < 1024) ? a[i] : (i < 2048 ? b[i - 1024] : c[i - 2048]);
}

// ---------------- h = pad ? 0 : h + P ----------------
__global__ void pad_red_kernel(float* __restrict__ h, const float* __restrict__ P,
                               const int* __restrict__ xlen)
{
    int row = blockIdx.x;
    int b = row >> 10, s = row & 1023;
    int len = xlen[b] >> 2;
    size_t off = (size_t)row * DMODEL;
    if (s >= len) {
        for (int d = threadIdx.x; d < DMODEL; d += 256) h[off + d] = 0.0f;
    } else {
        for (int d = threadIdx.x; d < DMODEL; d += 256) h[off + d] += P[off + d];
    }
}

// ---------------- h += P (split P0/P1) ----------------
__global__ void reduce2_kernel(float* __restrict__ h, const float* __restrict__ P0,
                               const float* __restrict__ P1, int prows0)
{
    int row = blockIdx.x;
    const float* P = (row < prows0) ? (P0 + (size_t)row * DMODEL)
                                    : (P1 + (size_t)(row - prows0) * DMODEL);
    size_t off = (size_t)row * DMODEL;
#pragma unroll
    for (int t = 0; t < 4; ++t) {
        int d = threadIdx.x + 256 * t;
        h[off + d] += P[d];
    }
}

// ---------------- LayerNorm (row of 1024), fp32 in, TO out; optional P fold ------
template<typename TO, bool RED>
__global__ void ln_kernel(float* __restrict__ x, const float* __restrict__ P0,
                          const float* __restrict__ sc, const float* __restrict__ bi,
                          TO* __restrict__ y)
{
    int row = blockIdx.x;
    float* xr = x + (size_t)row * DMODEL;
    const float* pr = RED ? (P0 + (size_t)row * DMODEL) : nullptr;
    float vals[4];
    float lsum = 0.0f, lsq = 0.0f;
#pragma unroll
    for (int t = 0; t < 4; ++t) {
        int d = threadIdx.x + 256 * t;
        float v = xr[d];
        if (RED) { v += pr[d]; xr[d] = v; }
        vals[t] = v; lsum += v; lsq += v * v;
    }
    for (int o = 32; o > 0; o >>= 1) {
        lsum += __shfl_down(lsum, o, 64);
        lsq  += __shfl_down(lsq,  o, 64);
    }
    __shared__ float s1[4], s2[4];
    int wv = threadIdx.x >> 6, ln = threadIdx.x & 63;
    if (ln == 0) { s1[wv] = lsum; s2[wv] = lsq; }
    __syncthreads();
    if (threadIdx.x == 0) {
        float a = s1[0] + s1[1] + s1[2] + s1[3];
        float b = s2[0] + s2[1] + s2[2] + s2[3];
        float mu = a * (1.0f / DMODEL);
        float var = b * (1.0f / DMODEL) - mu * mu;
        s1[0] = mu;
        s2[0] = rsqrtf(fmaxf(var, 0.0f) + 1e-5f);
    }
    __syncthreads();
    float mu = s1[0], inv = s2[0];
#pragma unroll
    for (int t = 0; t < 4; ++t) {
        int d = threadIdx.x + 256 * t;
        y[(size_t)row * DMODEL + d] = (TO)((vals[t] - mu) * inv * sc[d] + bi[d]);
    }
}

// ---------------- RoPE (in-place, bf16, strided) ----------------
__global__ void rope_kernel(bf16* __restrict__ q, bf16* __restrict__ k, int stride)
{
    size_t idx = (size_t)blockIdx.x * 256 + threadIdx.x;
    int d = idx & 63;
    size_t rest = idx >> 6;
    int hh = rest & 7;
    int s = (rest >> 3) & 1023;
    size_t base = (rest >> 3) * stride + (size_t)hh * DHEAD;
    // 10000^(-d/64) = 2^(-d * log2(10000)/64); v_exp_f32 is single-instruction
    float inv = exp2f((float)d * -0.20762050593045235f);
    float ang = (float)s * inv;
    float c, si;
    __sincosf(ang, &si, &c);
    {
        float x1 = (float)q[base + d], x2 = (float)q[base + 64 + d];
        q[base + d]      = (bf16)(x1 * c - x2 * si);
        q[base + 64 + d] = (bf16)(x1 * si + x2 * c);
    }
    {
        float x1 = (float)k[base + d], x2 = (float)k[base + 64 + d];
        k[base + d]      = (bf16)(x1 * c - x2 * si);
        k[base + 64 + d] = (bf16)(x1 * si + x2 * c);
    }
}

// ------- mean of v over s, two-stage: part[bh][chunk][d] then reduce -------
// Stage 1: 1024 blocks = 32 (b,h) x 32 chunks of 32 rows; 128 threads = d.
__global__ void vmean_part(const bf16* __restrict__ v, float* __restrict__ part,
                           int stride)
{
    int g = blockIdx.x;
    int chunk = g & 31;
    int bh = g >> 5;
    int b = bh >> 3, hh = bh & 7;
    int d = threadIdx.x;  // 128
    const bf16* base = v + ((size_t)(b * S_LEN + chunk * 32)) * stride
                         + hh * DHEAD + d;
    float acc = 0.0f;
#pragma unroll 4
    for (int s = 0; s < 32; ++s)
        acc += (float)base[(size_t)s * stride];
    part[((size_t)bh * 32 + chunk) * DHEAD + d] = acc;
}

// Stage 2: 32 blocks (b,h), 128 threads: sum 32 partials, scale by 1/S.
__global__ void vmean_fin(const float* __restrict__ part, float* __restrict__ vmean)
{
    int bh = blockIdx.x;
    int d = threadIdx.x;
    float acc = 0.0f;
#pragma unroll
    for (int c = 0; c < 32; ++c)
        acc += part[((size_t)bh * 32 + c) * DHEAD + d];
    vmean[(size_t)bh * DHEAD + d] = acc * (1.0f / S_LEN);
}

// ---------------- windowed attention, one wave per (b,h,i) ----------------
__global__ void attn_kernel(const bf16* __restrict__ q, const bf16* __restrict__ k,
                            const bf16* __restrict__ v, const float* __restrict__ vmean,
                            const int* __restrict__ xlen, bf16* __restrict__ ctx,
                            int stride)
{
    const int lane = threadIdx.x;  // 64
    int bhi = blockIdx.x;
    int i = bhi & 1023;
    int hh = (bhi >> 10) & 7;
    int b = bhi >> 13;
    int len = xlen[b] >> 2;
    size_t rowQ = ((size_t)(b * S_LEN + i)) * stride + hh * DHEAD;
    size_t rowC = ((size_t)(b * S_LEN + i)) * DMODEL + hh * DHEAD;
    int j0 = i - (WIN - 1); if (j0 < 0) j0 = 0;
    if (j0 >= len) {
        const float* vm = vmean + (size_t)(b * NHEAD + hh) * DHEAD;
        ctx[rowC + 2 * lane]     = (bf16)vm[2 * lane];
        ctx[rowC + 2 * lane + 1] = (bf16)vm[2 * lane + 1];
        return;
    }
    int j1 = i + LFWD; if (j1 > S_LEN - 1) j1 = S_LEN - 1;
    if (j1 > len - 1) j1 = len - 1;

    __shared__ float qs[DHEAD];
    __shared__ float p[128];
    qs[lane]      = (float)q[rowQ + lane];
    qs[lane + 64] = (float)q[rowQ + 64 + lane];
    __syncthreads();

    const float scale = 0.088388347648318447f;  // 1/sqrt(128)
    int jA = j0 + lane, jB = j0 + 64 + lane;
    float s0 = -1e30f, s1 = -1e30f;
    if (jA <= j1) {
        const short8* kr = (const short8*)(k + ((size_t)(b * S_LEN + jA)) * stride + hh * DHEAD);
        float acc = 0.0f;
#pragma unroll
        for (int c = 0; c < 16; ++c) {
            short8 kk = kr[c];
#pragma unroll
            for (int t = 0; t < 8; ++t)
                acc += qs[c * 8 + t] * bf2f((unsigned short)kk[t]);
        }
        s0 = acc * scale;
    }
    if (jB <= j1) {
        const short8* kr = (const short8*)(k + ((size_t)(b * S_LEN + jB)) * stride + hh * DHEAD);
        float acc = 0.0f;
#pragma unroll
        for (int c = 0; c < 16; ++c) {
            short8 kk = kr[c];
#pragma unroll
            for (int t = 0; t < 8; ++t)
                acc += qs[c * 8 + t] * bf2f((unsigned short)kk[t]);
        }
        s1 = acc * scale;
    }
    float m = fmaxf(s0, s1);
    for (int o = 32; o > 0; o >>= 1) m = fmaxf(m, __shfl_down(m, o, 64));
    m = __shfl(m, 0, 64);
    float e0 = (jA <= j1) ? __expf(s0 - m) : 0.0f;
    float e1 = (jB <= j1) ? __expf(s1 - m) : 0.0f;
    float ssum = e0 + e1;
    for (int o = 32; o > 0; o >>= 1) ssum += __shfl_down(ssum, o, 64);
    ssum = __shfl(ssum, 0, 64);
    float inv = 1.0f / fmaxf(ssum, 1e-30f);
    p[lane] = e0 * inv;
    p[lane + 64] = e1 * inv;
    __syncthreads();

    float a0 = 0.0f, a1 = 0.0f;
    for (int j = j0; j <= j1; ++j) {
        float pj = p[j - j0];
        const unsigned* vr = (const unsigned*)(v + ((size_t)(b * S_LEN + j)) * stride + hh * DHEAD);
        unsigned u = vr[lane];
        a0 += pj * bf2f((unsigned short)(u & 0xffff));
        a1 += pj * bf2f((unsigned short)(u >> 16));
    }
    ctx[rowC + 2 * lane]     = (bf16)a0;
    ctx[rowC + 2 * lane + 1] = (bf16)a1;
}

extern "C" void kernel_launch(void* const* d_in, const int* in_sizes, int n_in,
                              void* d_out, int out_size, void* d_ws, size_t ws_size,
                              hipStream_t stream)
{
    const float* x      = (const float*)d_in[0];
    const int*   xlen   = (const int*)d_in[1];
    const float* Wp     = (const float*)d_in[2];
    const float* bp     = (const float*)d_in[3];
    const float* ln1_s  = (const float*)d_in[4];
    const float* ln1_b  = (const float*)d_in[5];
    const float* Wq     = (const float*)d_in[6];
    const float* bq     = (const float*)d_in[7];
    const float* Wk     = (const float*)d_in[8];
    const float* bk     = (const float*)d_in[9];
    const float* Wv     = (const float*)d_in[10];
    const float* bv     = (const float*)d_in[11];
    const float* Wo     = (const float*)d_in[12];
    const float* bo     = (const float*)d_in[13];
    const float* ln2_s  = (const float*)d_in[14];
    const float* ln2_b  = (const float*)d_in[15];
    const float* W1     = (const float*)d_in[16];
    const float* b1     = (const float*)d_in[17];
    const float* W2     = (const float*)d_in[18];
    const float* b2     = (const float*)d_in[19];
    const float* lnf_s  = (const float*)d_in[20];
    const float* lnf_b  = (const float*)d_in[21];
    (void)in_sizes; (void)n_in; (void)out_size; (void)ws_size;

    // ---- workspace: 56 MB + ~28 KB ----
    const size_t MD = (size_t)M_ROWS * DMODEL;            // 4M elems
    float* h     = (float*)d_ws;                          // [0,16) MB
    bf16*  y     = (bf16*)(h + MD);                       // [16,24) MB (LN out / ctx)
    float* yfP   = (float*)(h + MD);                      // same region as fp32 (8 MB)
    bf16*  U     = y + MD;                                // [24,56) MB union
    bf16*  xb    = U;                                     // 16 MB (proj input)
    bf16*  qkv   = U;                                     // 24 MB, stride 3072
    bf16*  mid   = U;                                     // 32 MB (FFN mid)
    float* UfP   = (float*)U;                             // U as fp32 partial (16 MB)
    float* UfP2  = (float*)(U + 8 * 1024 * 1024);         // U second half fp32
    float* vmean = (float*)(U + 16 * 1024 * 1024);        // ws+56 MB, 16 KB
    float* bqkv  = vmean + BATCH * NHEAD * DHEAD;         // 12 KB
    // d_out (16 MB fp32) is scratch until final LN:
    bf16*  wt    = (bf16*)d_out;                          // [0,8) MB: weight^T
    float* doP   = (float*)((char*)d_out + 8 * 1024 * 1024); // [8,16) MB fp32 partial
    float* vpart = doP;   // 512 KB vmean partials; doP region is dead during attn

    const int QS = 3 * DMODEL;   // qkv row stride

    dim3 blk(256);
    dim3 gSK(DMODEL / 128, M_ROWS / 128, 2);              // split-K grid, 512 blocks

    // xb = bf16(x); h = xb @ Wp^T + bp (split-K, P in U upper half); pad+reduce
    cvt_kernel<<<(2 * MD) / (256 * 4), blk, 0, stream>>>(x, xb);
    transpose_kernel<<<dim3(DMODEL / 32, 2048 / 32), blk, 0, stream>>>(Wp, wt, 2048, DMODEL, DMODEL);
    mfma_gemm_sk<<<gSK, blk, 0, stream>>>(xb, wt, bp, h, nullptr,
                                          UfP2, nullptr, M_ROWS, M_ROWS, DMODEL, 2048);
    pad_red_kernel<<<M_ROWS, blk, 0, stream>>>(h, UfP2, xlen);

    for (int l = 0; l < 4; ++l) {
        const size_t wD  = (size_t)l * DMODEL * DMODEL;
        const size_t wF  = (size_t)l * DMODEL * DFF;   // W1 (1024 x 4096)
        const size_t wF2 = (size_t)l * DFF * DMODEL;   // W2 (4096 x 1024)
        const size_t vD  = (size_t)l * DMODEL;
        const size_t vF  = (size_t)l * DFF;

        ln_kernel<bf16, false><<<M_ROWS, blk, 0, stream>>>(h, nullptr,
                                                           ln1_s + vD, ln1_b + vD, y);

        // fused QKV (768 blocks, no split)
        transpose_kernel<<<dim3(32, 32), blk, 0, stream>>>(Wq + wD, wt, DMODEL, DMODEL, DMODEL);
        transpose_kernel<<<dim3(32, 32), blk, 0, stream>>>(Wk + wD, wt + MD / 4, DMODEL, DMODEL, DMODEL);
        transpose_kernel<<<dim3(32, 32), blk, 0, stream>>>(Wv + wD, wt + MD / 2, DMODEL, DMODEL, DMODEL);
        concat3_kernel<<<12, blk, 0, stream>>>(bq + vD, bk + vD, bv + vD, bqkv);
        mfma_gemm<bf16><<<dim3(3 * DMODEL / 128, M_ROWS / 128), blk, 0, stream>>>(
            y, wt, bqkv, qkv, M_ROWS, 3 * DMODEL, DMODEL, 0);

        bf16* qb = qkv;
        bf16* kb = qkv + DMODEL;
        bf16* vb = qkv + 2 * DMODEL;
        rope_kernel<<<(M_ROWS * NHEAD * 64) / 256, blk, 0, stream>>>(qb, kb, QS);
        vmean_part<<<BATCH * NHEAD * 32, dim3(DHEAD), 0, stream>>>(vb, vpart, QS);
        vmean_fin<<<BATCH * NHEAD, dim3(DHEAD), 0, stream>>>(vpart, vmean);
        attn_kernel<<<BATCH * NHEAD * S_LEN, dim3(64), 0, stream>>>(qb, kb, vb, vmean,
                                                                    xlen, y, QS);

        // h = h + ctx @ Wo^T + bo  (split-K; P in U[0:16) — qkv dead)
        transpose_kernel<<<dim3(32, 32), blk, 0, stream>>>(Wo + wD, wt, DMODEL, DMODEL, DMODEL);
        mfma_gemm_sk<<<gSK, blk, 0, stream>>>(y, wt, bo + vD, h, h,
                                              UfP, nullptr, M_ROWS, M_ROWS, DMODEL, 1024);

        // ln2 fused with Wo's partial reduce: h += P; y = LN(h)
        ln_kernel<bf16, true><<<M_ROWS, blk, 0, stream>>>(h, UfP,
                                                          ln2_s + vD, ln2_b + vD, y);

        // FFN1 full width: mid = silu(y @ W1^T + b1)   (1024 blocks)
        transpose_kernel<<<dim3(DFF / 32, DMODEL / 32), blk, 0, stream>>>(
            W1 + wF, wt, DMODEL, DFF, DFF);
        mfma_gemm<bf16><<<dim3(DFF / 128, M_ROWS / 128), blk, 0, stream>>>(
            y, wt, b1 + vF, mid, M_ROWS, DFF, DMODEL, 1);

        // FFN2 split-K: h = h + mid @ W2^T + b2; P split: rows<2048 -> y-region,
        // rest -> d_out[8:16)  (y dead after FFN1; both regions free)
        transpose_kernel<<<dim3(DMODEL / 32, DFF / 32), blk, 0, stream>>>(
            W2 + wF2, wt, DFF, DMODEL, DMODEL);
        mfma_gemm_sk<<<gSK, blk, 0, stream>>>(mid, wt, b2 + vD, h, h,
                                              yfP, doP, 2048, M_ROWS, DMODEL, DFF);
        reduce2_kernel<<<M_ROWS, blk, 0, stream>>>(h, yfP, doP, 2048);
    }

    ln_kernel<float, false><<<M_ROWS, blk, 0, stream>>>(h, nullptr, lnf_s, lnf_b,
                                                        (float*)d_out);
}

// Round 4
// 1465.504 us; speedup vs baseline: 1.4097x; 1.1584x over previous
//
#include <hip/hip_runtime.h>
#include <hip/hip_bf16.h>
#include <math.h>

typedef __hip_bfloat16 bf16;
typedef __attribute__((ext_vector_type(8))) short short8;
typedef __attribute__((ext_vector_type(4))) float f32x4;

#define S_LEN 1024
#define BATCH 4
#define M_ROWS 4096
#define DMODEL 1024
#define DFF 4096
#define NHEAD 8
#define DHEAD 128
#define WIN 100
#define LFWD 20

__device__ __forceinline__ void gl_lds16(const void* g, void* l) {
    __builtin_amdgcn_global_load_lds(
        (const __attribute__((address_space(1))) void*)g,
        (__attribute__((address_space(3))) void*)l, 16, 0, 0);
}

__device__ __forceinline__ float bf2f(unsigned short u) {
    return __uint_as_float(((unsigned)u) << 16);
}

// XCD-aware bijective swizzle (nb is always a multiple of 8 here):
__device__ __forceinline__ int xcd_swz(int flat, int nb) {
    return (flat & 7) * (nb >> 3) + (flat >> 3);
}

// ---------------- MFMA GEMM (no split): C = act(A @ Bt^T + bias) ----------------
template<typename TC>
__global__ __launch_bounds__(256)
void mfma_gemm(const bf16* __restrict__ A, const bf16* __restrict__ Bt,
               const float* __restrict__ bias, TC* __restrict__ C,
               int M, int N, int K, int act)
{
    __shared__ bf16 As[2][128 * 32];
    __shared__ bf16 Bs[2][128 * 32];
    const int gx = gridDim.x;
    const int nb = gx * gridDim.y;
    const int swz = xcd_swz(blockIdx.x + gx * blockIdx.y, nb);
    const int bn = (swz % gx) * 128;
    const int bm = (swz / gx) * 128;
    const int tid = threadIdx.x;
    const int w = tid >> 6, lane = tid & 63;
    const int wm = (w & 1) * 64, wn = (w >> 1) * 64;

    const int srow = w * 32 + (lane >> 2);
    const int selem = (lane & 3) * 8;
    const bf16* ga0 = A + (size_t)(bm + srow) * K + selem;
    const bf16* ga1 = ga0 + (size_t)16 * K;
    const bf16* gb0 = Bt + (size_t)(bn + srow) * K + selem;
    const bf16* gb1 = gb0 + (size_t)16 * K;
    const int l0 = (w * 32) * 32;
    const int l1 = (w * 32 + 16) * 32;

    f32x4 acc[4][4] = {};
    const int koff = (lane >> 4) * 8;
    const int fr = lane & 15;

    gl_lds16(ga0, As[0] + l0); gl_lds16(ga1, As[0] + l1);
    gl_lds16(gb0, Bs[0] + l0); gl_lds16(gb1, Bs[0] + l1);
    ga0 += 32; ga1 += 32; gb0 += 32; gb1 += 32;
    __syncthreads();

    const int nk = K >> 5;
    int cur = 0;
    for (int t = 0; t < nk; ++t) {
        if (t + 1 < nk) {
            bf16* a = As[cur ^ 1]; bf16* b = Bs[cur ^ 1];
            gl_lds16(ga0, a + l0); gl_lds16(ga1, a + l1);
            gl_lds16(gb0, b + l0); gl_lds16(gb1, b + l1);
            ga0 += 32; ga1 += 32; gb0 += 32; gb1 += 32;
        }
        short8 af[4], bfr[4];
#pragma unroll
        for (int i = 0; i < 4; ++i)
            af[i] = *(const short8*)(As[cur] + (wm + i * 16 + fr) * 32 + koff);
#pragma unroll
        for (int j = 0; j < 4; ++j)
            bfr[j] = *(const short8*)(Bs[cur] + (wn + j * 16 + fr) * 32 + koff);
#pragma unroll
        for (int i = 0; i < 4; ++i)
#pragma unroll
            for (int j = 0; j < 4; ++j)
                acc[i][j] = __builtin_amdgcn_mfma_f32_16x16x32_bf16(
                    af[i], bfr[j], acc[i][j], 0, 0, 0);
        __syncthreads();
        cur ^= 1;
    }

    const int cq = lane >> 4, cn = lane & 15;
#pragma unroll
    for (int i = 0; i < 4; ++i) {
#pragma unroll
        for (int r = 0; r < 4; ++r) {
            int row = bm + wm + i * 16 + cq * 4 + r;
#pragma unroll
            for (int j = 0; j < 4; ++j) {
                int col = bn + wn + j * 16 + cn;
                float v = acc[i][j][r] + bias[col];
                if (act) v = v / (1.0f + __expf(-v));   // silu
                C[(size_t)row * N + col] = (TC)v;
            }
        }
    }
}

// ---------- MFMA GEMM split-K=2: z=0 -> C=acc+bias(+resid), z=1 -> P=acc ----------
__global__ __launch_bounds__(256)
void mfma_gemm_sk(const bf16* __restrict__ A, const bf16* __restrict__ Bt,
                  const float* __restrict__ bias, float* __restrict__ C,
                  const float* __restrict__ resid,
                  float* __restrict__ P0, float* __restrict__ P1, int prows0,
                  int M, int N, int K)
{
    __shared__ bf16 As[2][128 * 32];
    __shared__ bf16 Bs[2][128 * 32];
    const int gx = gridDim.x, gy = gridDim.y;
    const int nb = gx * gy * 2;
    const int swz = xcd_swz(blockIdx.x + gx * (blockIdx.y + gy * blockIdx.z), nb);
    const int bn = (swz % gx) * 128;
    const int bm = ((swz / gx) % gy) * 128;
    const int z  = swz / (gx * gy);
    const int khalf = K >> 1;
    const int kstart = z * khalf;
    const int tid = threadIdx.x;
    const int w = tid >> 6, lane = tid & 63;
    const int wm = (w & 1) * 64, wn = (w >> 1) * 64;

    const int srow = w * 32 + (lane >> 2);
    const int selem = (lane & 3) * 8;
    const bf16* ga0 = A + (size_t)(bm + srow) * K + kstart + selem;
    const bf16* ga1 = ga0 + (size_t)16 * K;
    const bf16* gb0 = Bt + (size_t)(bn + srow) * K + kstart + selem;
    const bf16* gb1 = gb0 + (size_t)16 * K;
    const int l0 = (w * 32) * 32;
    const int l1 = (w * 32 + 16) * 32;

    f32x4 acc[4][4] = {};
    const int koff = (lane >> 4) * 8;
    const int fr = lane & 15;

    gl_lds16(ga0, As[0] + l0); gl_lds16(ga1, As[0] + l1);
    gl_lds16(gb0, Bs[0] + l0); gl_lds16(gb1, Bs[0] + l1);
    ga0 += 32; ga1 += 32; gb0 += 32; gb1 += 32;
    __syncthreads();

    const int nk = khalf >> 5;
    int cur = 0;
    for (int t = 0; t < nk; ++t) {
        if (t + 1 < nk) {
            bf16* a = As[cur ^ 1]; bf16* b = Bs[cur ^ 1];
            gl_lds16(ga0, a + l0); gl_lds16(ga1, a + l1);
            gl_lds16(gb0, b + l0); gl_lds16(gb1, b + l1);
            ga0 += 32; ga1 += 32; gb0 += 32; gb1 += 32;
        }
        short8 af[4], bfr[4];
#pragma unroll
        for (int i = 0; i < 4; ++i)
            af[i] = *(const short8*)(As[cur] + (wm + i * 16 + fr) * 32 + koff);
#pragma unroll
        for (int j = 0; j < 4; ++j)
            bfr[j] = *(const short8*)(Bs[cur] + (wn + j * 16 + fr) * 32 + koff);
#pragma unroll
        for (int i = 0; i < 4; ++i)
#pragma unroll
            for (int j = 0; j < 4; ++j)
                acc[i][j] = __builtin_amdgcn_mfma_f32_16x16x32_bf16(
                    af[i], bfr[j], acc[i][j], 0, 0, 0);
        __syncthreads();
        cur ^= 1;
    }

    const int cq = lane >> 4, cn = lane & 15;
#pragma unroll
    for (int i = 0; i < 4; ++i) {
#pragma unroll
        for (int r = 0; r < 4; ++r) {
            int row = bm + wm + i * 16 + cq * 4 + r;
#pragma unroll
            for (int j = 0; j < 4; ++j) {
                int col = bn + wn + j * 16 + cn;
                float v = acc[i][j][r];
                if (z == 0) {
                    v += bias[col];
                    if (resid) v += resid[(size_t)row * N + col];
                    C[(size_t)row * N + col] = v;
                } else {
                    float* P = (row < prows0) ? (P0 + (size_t)row * N + col)
                                              : (P1 + (size_t)(row - prows0) * N + col);
                    *P = v;
                }
            }
        }
    }
}

// -------- transpose+cast: W (K x N fp32, row stride ld) -> Wt (N x K bf16) --------
__global__ void transpose_kernel(const float* __restrict__ W, bf16* __restrict__ Wt,
                                 int K, int N, int ld)
{
    __shared__ float t[32][33];
    const int n0 = blockIdx.x * 32, k0 = blockIdx.y * 32;
    const int tx = threadIdx.x & 31, ty = threadIdx.x >> 5;
#pragma unroll
    for (int i = 0; i < 32; i += 8)
        t[ty + i][tx] = W[(size_t)(k0 + ty + i) * ld + n0 + tx];
    __syncthreads();
#pragma unroll
    for (int i = 0; i < 32; i += 8)
        Wt[(size_t)(n0 + ty + i) * K + k0 + tx] = (bf16)t[tx][ty + i];
}

// -------- v (qkv col 2048+) -> vt[b][h][d][s] bf16 --------
__global__ void vtrans_kernel(const bf16* __restrict__ qkv, bf16* __restrict__ vt)
{
    __shared__ bf16 t[32][33];
    const int bh = blockIdx.z;
    const int s0 = blockIdx.x * 32, d0 = blockIdx.y * 32;
    const int b = bh >> 3, h = bh & 7;
    const int tx = threadIdx.x & 31, ty = threadIdx.x >> 5;
#pragma unroll
    for (int i = 0; i < 32; i += 8)
        t[ty + i][tx] = qkv[(size_t)(b * S_LEN + s0 + ty + i) * 3072 + 2048
                            + h * DHEAD + d0 + tx];
    __syncthreads();
#pragma unroll
    for (int i = 0; i < 32; i += 8)
        vt[(size_t)(bh * DHEAD + d0 + ty + i) * 1024 + s0 + tx] = t[tx][ty + i];
}

// ---------------- fp32 -> bf16 convert ----------------
__global__ void cvt_kernel(const float* __restrict__ s, bf16* __restrict__ d)
{
    size_t i = ((size_t)blockIdx.x * 256 + threadIdx.x) * 4;
    float4 v = *(const float4*)(s + i);
    d[i] = (bf16)v.x; d[i + 1] = (bf16)v.y; d[i + 2] = (bf16)v.z; d[i + 3] = (bf16)v.w;
}

// ---------------- concat 3 bias vectors of 1024 fp32 ----------------
__global__ void concat3_kernel(const float* __restrict__ a, const float* __restrict__ b,
                               const float* __restrict__ c, float* __restrict__ o)
{
    int i = blockIdx.x * 256 + threadIdx.x;
    o[i] = (i < 1024) ? a[i] : (i < 2048 ? b[i - 1024] : c[i - 2048]);
}

// ---------------- h = pad ? 0 : h + P ----------------
__global__ void pad_red_kernel(float* __restrict__ h, const float* __restrict__ P,
                               const int* __restrict__ xlen)
{
    int row = blockIdx.x;
    int b = row >> 10, s = row & 1023;
    int len = xlen[b] >> 2;
    size_t off = (size_t)row * DMODEL;
    if (s >= len) {
        for (int d = threadIdx.x; d < DMODEL; d += 256) h[off + d] = 0.0f;
    } else {
        for (int d = threadIdx.x; d < DMODEL; d += 256) h[off + d] += P[off + d];
    }
}

// ---------------- h += P (split P0/P1) ----------------
__global__ void reduce2_kernel(float* __restrict__ h, const float* __restrict__ P0,
                               const float* __restrict__ P1, int prows0)
{
    int row = blockIdx.x;
    const float* P = (row < prows0) ? (P0 + (size_t)row * DMODEL)
                                    : (P1 + (size_t)(row - prows0) * DMODEL);
    size_t off = (size_t)row * DMODEL;
#pragma unroll
    for (int t = 0; t < 4; ++t) {
        int d = threadIdx.x + 256 * t;
        h[off + d] += P[d];
    }
}

// ---------------- LayerNorm (row of 1024) ----------------
template<typename TO, bool RED>
__global__ void ln_kernel(float* __restrict__ x, const float* __restrict__ P0,
                          const float* __restrict__ sc, const float* __restrict__ bi,
                          TO* __restrict__ y)
{
    int row = blockIdx.x;
    float* xr = x + (size_t)row * DMODEL;
    const float* pr = RED ? (P0 + (size_t)row * DMODEL) : nullptr;
    float vals[4];
    float lsum = 0.0f, lsq = 0.0f;
#pragma unroll
    for (int t = 0; t < 4; ++t) {
        int d = threadIdx.x + 256 * t;
        float v = xr[d];
        if (RED) { v += pr[d]; xr[d] = v; }
        vals[t] = v; lsum += v; lsq += v * v;
    }
    for (int o = 32; o > 0; o >>= 1) {
        lsum += __shfl_down(lsum, o, 64);
        lsq  += __shfl_down(lsq,  o, 64);
    }
    __shared__ float s1[4], s2[4];
    int wv = threadIdx.x >> 6, ln = threadIdx.x & 63;
    if (ln == 0) { s1[wv] = lsum; s2[wv] = lsq; }
    __syncthreads();
    if (threadIdx.x == 0) {
        float a = s1[0] + s1[1] + s1[2] + s1[3];
        float b = s2[0] + s2[1] + s2[2] + s2[3];
        float mu = a * (1.0f / DMODEL);
        float var = b * (1.0f / DMODEL) - mu * mu;
        s1[0] = mu;
        s2[0] = rsqrtf(fmaxf(var, 0.0f) + 1e-5f);
    }
    __syncthreads();
    float mu = s1[0], inv = s2[0];
#pragma unroll
    for (int t = 0; t < 4; ++t) {
        int d = threadIdx.x + 256 * t;
        y[(size_t)row * DMODEL + d] = (TO)((vals[t] - mu) * inv * sc[d] + bi[d]);
    }
}

// ---------------- RoPE (in-place, bf16, strided) ----------------
__global__ void rope_kernel(bf16* __restrict__ q, bf16* __restrict__ k, int stride)
{
    size_t idx = (size_t)blockIdx.x * 256 + threadIdx.x;
    int d = idx & 63;
    size_t rest = idx >> 6;
    int hh = rest & 7;
    int s = (rest >> 3) & 1023;
    size_t base = (rest >> 3) * stride + (size_t)hh * DHEAD;
    float inv = exp2f((float)d * -0.20762050593045235f);
    float ang = (float)s * inv;
    float c, si;
    __sincosf(ang, &si, &c);
    {
        float x1 = (float)q[base + d], x2 = (float)q[base + 64 + d];
        q[base + d]      = (bf16)(x1 * c - x2 * si);
        q[base + 64 + d] = (bf16)(x1 * si + x2 * c);
    }
    {
        float x1 = (float)k[base + d], x2 = (float)k[base + 64 + d];
        k[base + d]      = (bf16)(x1 * c - x2 * si);
        k[base + 64 + d] = (bf16)(x1 * si + x2 * c);
    }
}

// ------- mean of v over s, two-stage -------
__global__ void vmean_part(const bf16* __restrict__ v, float* __restrict__ part,
                           int stride)
{
    int g = blockIdx.x;
    int chunk = g & 31;
    int bh = g >> 5;
    int b = bh >> 3, hh = bh & 7;
    int d = threadIdx.x;
    const bf16* base = v + ((size_t)(b * S_LEN + chunk * 32)) * stride
                         + hh * DHEAD + d;
    float acc = 0.0f;
#pragma unroll 4
    for (int s = 0; s < 32; ++s)
        acc += (float)base[(size_t)s * stride];
    part[((size_t)bh * 32 + chunk) * DHEAD + d] = acc;
}

__global__ void vmean_fin(const float* __restrict__ part, float* __restrict__ vmean)
{
    int bh = blockIdx.x;
    int d = threadIdx.x;
    float acc = 0.0f;
#pragma unroll
    for (int c = 0; c < 32; ++c)
        acc += part[((size_t)bh * 32 + c) * DHEAD + d];
    vmean[(size_t)bh * DHEAD + d] = acc * (1.0f / S_LEN);
}

// ============== MFMA windowed attention ==============
// Block = 128 thr (2 waves) per (b,h, 32-query tile). <=3 KV tiles of 64 keys.
// K lds: [64][128] bf16, elem ^= (row&7)<<3 (src pre-swizzled, read swizzled).
// Vt lds: [128][64] same idea. P lds per wave: [16][192] bf16, swizzled.
__global__ __launch_bounds__(128)
void attn_mfma(const bf16* __restrict__ qkv, const bf16* __restrict__ vt_g,
               const float* __restrict__ vmean, const int* __restrict__ xlen,
               bf16* __restrict__ ctx)
{
    __shared__ bf16 KV[2][64 * 128];     // 2 x 16 KB
    __shared__ bf16 P[2][16 * 192];      // per-wave P, 12 KB

    const int qt = blockIdx.x;           // 32 tiles of 32 queries
    const int bh = blockIdx.y;           // b*8+h
    const int b = bh >> 3, h = bh & 7;
    const int tid = threadIdx.x;
    const int w = tid >> 6, l = tid & 63;
    const int qlo = qt * 32;
    const int len = xlen[b] >> 2;

    // valid kv tiles (64-wide), covering [max(0,qlo-128), ...] ⊇ window
    int s0 = qlo - 128; if (s0 < 0) s0 = 0;
    const int jmax = qlo + 51;
    int k0t[3]; int nt = 0;
#pragma unroll
    for (int t = 0; t < 3; ++t) {
        int k0 = s0 + t * 64;
        if (k0 <= jmax && k0 < len) { k0t[nt] = k0; ++nt; }
    }

    const bf16* qbase = qkv + (size_t)(b * S_LEN) * 3072 + h * DHEAD;
    const bf16* kbase = qbase + DMODEL;

    // Q fragments: wave w owns queries qlo + w*16 + (l&15)
    short8 qa[4];
    {
        const bf16* qr = qbase + (size_t)(qlo + w * 16 + (l & 15)) * 3072 + (l >> 4) * 8;
#pragma unroll
        for (int kk = 0; kk < 4; ++kk)
            qa[kk] = *(const short8*)(qr + kk * 32);
    }

    auto stageK = [&](int k0, int buf) {
#pragma unroll
        for (int c = 0; c < 8; ++c) {
            int rl = w * 32 + c * 4 + (l >> 4);
            int sr = k0 + rl; if (sr > S_LEN - 1) sr = S_LEN - 1;  // in-bounds (masked)
            int sc = ((l & 15) * 8) ^ ((rl & 7) << 3);
            gl_lds16(kbase + (size_t)sr * 3072 + sc,
                     &KV[buf][(w * 32 + c * 4) * 128]);
        }
    };
    auto stageV = [&](int k0, int buf) {
#pragma unroll
        for (int c = 0; c < 8; ++c) {
            int d = w * 64 + c * 8 + (l >> 3);
            int js = ((l & 7) * 8) ^ ((d & 7) << 3);
            int s = k0 + js; if (s > S_LEN - 8) s = S_LEN - 8;     // in-bounds (masked)
            gl_lds16(vt_g + (size_t)(bh * 128 + d) * 1024 + s,
                     &KV[buf][(w * 64 + c * 8) * 64]);
        }
    };

    f32x4 sf[3][4] = {};

    auto sphase = [&](int t, int buf) {
#pragma unroll
        for (int jb = 0; jb < 4; ++jb) {
            int row = jb * 16 + (l & 15);
#pragma unroll
            for (int kk = 0; kk < 4; ++kk) {
                int kel = (kk * 32 + (l >> 4) * 8) ^ ((row & 7) << 3);
                short8 kf = *(const short8*)(&KV[buf][row * 128 + kel]);
                sf[t][jb] = __builtin_amdgcn_mfma_f32_16x16x32_bf16(
                    qa[kk], kf, sf[t][jb], 0, 0, 0);
            }
        }
    };

    // ---- phase A: S tiles ----
    if (nt > 0) stageK(k0t[0], 0);
    __syncthreads();
    if (nt > 1) stageK(k0t[1], 1);
    if (nt > 0) sphase(0, 0);
    __syncthreads();
    if (nt > 2) stageK(k0t[2], 0);
    if (nt > 1) sphase(1, 1);
    __syncthreads();
    if (nt > 2) sphase(2, 0);
    if (nt > 0) stageV(k0t[0], 1);     // overlaps softmax below

    // ---- softmax (registers) ----
    const float scale = 0.088388347648318447f;  // 1/sqrt(128)
    float mr[4] = {-1e30f, -1e30f, -1e30f, -1e30f};
#pragma unroll
    for (int t = 0; t < 3; ++t) if (t < nt) {
#pragma unroll
        for (int jb = 0; jb < 4; ++jb) {
            int j = k0t[t] + jb * 16 + (l & 15);
            bool jok = (j < len);
#pragma unroll
            for (int r = 0; r < 4; ++r) {
                int i = qlo + w * 16 + ((l >> 4) << 2) + r;
                float v = sf[t][jb][r] * scale;
                bool ok = jok && (j - i <= LFWD) && (i - j < WIN);
                v = ok ? v : -1e30f;
                sf[t][jb][r] = v;
                mr[r] = fmaxf(mr[r], v);
            }
        }
    }
#pragma unroll
    for (int o = 1; o <= 8; o <<= 1)
#pragma unroll
        for (int r = 0; r < 4; ++r)
            mr[r] = fmaxf(mr[r], __shfl_xor(mr[r], o, 64));

    float lr[4] = {0.0f, 0.0f, 0.0f, 0.0f};
#pragma unroll
    for (int t = 0; t < 3; ++t) if (t < nt) {
#pragma unroll
        for (int jb = 0; jb < 4; ++jb) {
#pragma unroll
            for (int r = 0; r < 4; ++r) {
                int q = ((l >> 4) << 2) + r;
                int jrel = t * 64 + jb * 16 + (l & 15);
                float e = __expf(sf[t][jb][r] - mr[r]);
                lr[r] += e;
                P[w][q * 192 + (jrel ^ ((q & 7) << 3))] = (bf16)e;
            }
        }
    }
#pragma unroll
    for (int o = 1; o <= 8; o <<= 1)
#pragma unroll
        for (int r = 0; r < 4; ++r)
            lr[r] += __shfl_xor(lr[r], o, 64);
    float inv[4];
#pragma unroll
    for (int r = 0; r < 4; ++r) inv[r] = 1.0f / fmaxf(lr[r], 1e-30f);

    __syncthreads();   // V tile0 staged + P visible

    // ---- phase B: O = P @ V ----
    f32x4 acc[8] = {};
    auto pv = [&](int ti, int buf) {
#pragma unroll
        for (int s32 = 0; s32 < 2; ++s32) {
            int q = l & 15;
            int jr8 = ti * 64 + s32 * 32 + (l >> 4) * 8;
            short8 pa = *(const short8*)(&P[w][q * 192 + (jr8 ^ ((q & 7) << 3))]);
#pragma unroll
            for (int db = 0; db < 8; ++db) {
                int d = db * 16 + (l & 15);
                int je = (s32 * 32 + (l >> 4) * 8) ^ ((d & 7) << 3);
                short8 vf = *(const short8*)(&KV[buf][d * 64 + je]);
                acc[db] = __builtin_amdgcn_mfma_f32_16x16x32_bf16(
                    pa, vf, acc[db], 0, 0, 0);
            }
        }
    };

    if (nt > 1) stageV(k0t[1], 0);
    if (nt > 0) pv(0, 1);
    __syncthreads();
    if (nt > 2) stageV(k0t[2], 1);
    if (nt > 1) pv(1, 0);
    __syncthreads();
    if (nt > 2) pv(2, 1);

    // ---- epilogue ----
    const float* vm = vmean + (size_t)bh * DHEAD;
    float vmr[8];
#pragma unroll
    for (int db = 0; db < 8; ++db) vmr[db] = vm[db * 16 + (l & 15)];
#pragma unroll
    for (int r = 0; r < 4; ++r) {
        int i = qlo + w * 16 + ((l >> 4) << 2) + r;
        bf16* crow = ctx + (size_t)(b * S_LEN + i) * DMODEL + h * DHEAD;
        bool em = mr[r] < -1e29f;
        float iv = inv[r];
#pragma unroll
        for (int db = 0; db < 8; ++db) {
            float v = em ? vmr[db] : acc[db][r] * iv;
            crow[db * 16 + (l & 15)] = (bf16)v;
        }
    }
}

extern "C" void kernel_launch(void* const* d_in, const int* in_sizes, int n_in,
                              void* d_out, int out_size, void* d_ws, size_t ws_size,
                              hipStream_t stream)
{
    const float* x      = (const float*)d_in[0];
    const int*   xlen   = (const int*)d_in[1];
    const float* Wp     = (const float*)d_in[2];
    const float* bp     = (const float*)d_in[3];
    const float* ln1_s  = (const float*)d_in[4];
    const float* ln1_b  = (const float*)d_in[5];
    const float* Wq     = (const float*)d_in[6];
    const float* bq     = (const float*)d_in[7];
    const float* Wk     = (const float*)d_in[8];
    const float* bk     = (const float*)d_in[9];
    const float* Wv     = (const float*)d_in[10];
    const float* bv     = (const float*)d_in[11];
    const float* Wo     = (const float*)d_in[12];
    const float* bo     = (const float*)d_in[13];
    const float* ln2_s  = (const float*)d_in[14];
    const float* ln2_b  = (const float*)d_in[15];
    const float* W1     = (const float*)d_in[16];
    const float* b1     = (const float*)d_in[17];
    const float* W2     = (const float*)d_in[18];
    const float* b2     = (const float*)d_in[19];
    const float* lnf_s  = (const float*)d_in[20];
    const float* lnf_b  = (const float*)d_in[21];
    (void)in_sizes; (void)n_in; (void)out_size; (void)ws_size;

    const size_t MD = (size_t)M_ROWS * DMODEL;
    float* h     = (float*)d_ws;                          // [0,16) MB
    bf16*  y     = (bf16*)(h + MD);                       // [16,24) MB
    float* yfP   = (float*)(h + MD);
    bf16*  U     = y + MD;                                // [24,56) MB union
    bf16*  xb    = U;
    bf16*  qkv   = U;
    bf16*  mid   = U;
    float* UfP   = (float*)U;
    float* UfP2  = (float*)(U + 8 * 1024 * 1024);
    float* vmean = (float*)(U + 16 * 1024 * 1024);
    float* bqkv  = vmean + BATCH * NHEAD * DHEAD;
    bf16*  wt    = (bf16*)d_out;                          // [0,8) MB of d_out
    float* doP   = (float*)((char*)d_out + 8 * 1024 * 1024);
    float* vpart = doP;                                   // vmean partials
    bf16*  vt_g  = (bf16*)d_out;                          // V^T [32][128][1024], 8 MB
                                                          // (wt dead during attn)
    const int QS = 3 * DMODEL;

    dim3 blk(256);
    dim3 gSK(DMODEL / 128, M_ROWS / 128, 2);

    cvt_kernel<<<(2 * MD) / (256 * 4), blk, 0, stream>>>(x, xb);
    transpose_kernel<<<dim3(DMODEL / 32, 2048 / 32), blk, 0, stream>>>(Wp, wt, 2048, DMODEL, DMODEL);
    mfma_gemm_sk<<<gSK, blk, 0, stream>>>(xb, wt, bp, h, nullptr,
                                          UfP2, nullptr, M_ROWS, M_ROWS, DMODEL, 2048);
    pad_red_kernel<<<M_ROWS, blk, 0, stream>>>(h, UfP2, xlen);

    for (int l = 0; l < 4; ++l) {
        const size_t wD  = (size_t)l * DMODEL * DMODEL;
        const size_t wF  = (size_t)l * DMODEL * DFF;
        const size_t wF2 = (size_t)l * DFF * DMODEL;
        const size_t vD  = (size_t)l * DMODEL;
        const size_t vF  = (size_t)l * DFF;

        ln_kernel<bf16, false><<<M_ROWS, blk, 0, stream>>>(h, nullptr,
                                                           ln1_s + vD, ln1_b + vD, y);

        transpose_kernel<<<dim3(32, 32), blk, 0, stream>>>(Wq + wD, wt, DMODEL, DMODEL, DMODEL);
        transpose_kernel<<<dim3(32, 32), blk, 0, stream>>>(Wk + wD, wt + MD / 4, DMODEL, DMODEL, DMODEL);
        transpose_kernel<<<dim3(32, 32), blk, 0, stream>>>(Wv + wD, wt + MD / 2, DMODEL, DMODEL, DMODEL);
        concat3_kernel<<<12, blk, 0, stream>>>(bq + vD, bk + vD, bv + vD, bqkv);
        mfma_gemm<bf16><<<dim3(3 * DMODEL / 128, M_ROWS / 128), blk, 0, stream>>>(
            y, wt, bqkv, qkv, M_ROWS, 3 * DMODEL, DMODEL, 0);

        bf16* qb = qkv;
        bf16* kb = qkv + DMODEL;
        bf16* vb = qkv + 2 * DMODEL;
        rope_kernel<<<(M_ROWS * NHEAD * 64) / 256, blk, 0, stream>>>(qb, kb, QS);
        vtrans_kernel<<<dim3(32, 4, 32), blk, 0, stream>>>(qkv, vt_g);   // wt now dead
        vmean_part<<<BATCH * NHEAD * 32, dim3(DHEAD), 0, stream>>>(vb, vpart, QS);
        vmean_fin<<<BATCH * NHEAD, dim3(DHEAD), 0, stream>>>(vpart, vmean);
        attn_mfma<<<dim3(32, 32), dim3(128), 0, stream>>>(qkv, vt_g, vmean, xlen, y);

        transpose_kernel<<<dim3(32, 32), blk, 0, stream>>>(Wo + wD, wt, DMODEL, DMODEL, DMODEL);
        mfma_gemm_sk<<<gSK, blk, 0, stream>>>(y, wt, bo + vD, h, h,
                                              UfP, nullptr, M_ROWS, M_ROWS, DMODEL, 1024);

        ln_kernel<bf16, true><<<M_ROWS, blk, 0, stream>>>(h, UfP,
                                                          ln2_s + vD, ln2_b + vD, y);

        transpose_kernel<<<dim3(DFF / 32, DMODEL / 32), blk, 0, stream>>>(
            W1 + wF, wt, DMODEL, DFF, DFF);
        mfma_gemm<bf16><<<dim3(DFF / 128, M_ROWS / 128), blk, 0, stream>>>(
            y, wt, b1 + vF, mid, M_ROWS, DFF, DMODEL, 1);

        transpose_kernel<<<dim3(DMODEL / 32, DFF / 32), blk, 0, stream>>>(
            W2 + wF2, wt, DFF, DMODEL, DMODEL);
        mfma_gemm_sk<<<gSK, blk, 0, stream>>>(mid, wt, b2 + vD, h, h,
                                              yfP, doP, 2048, M_ROWS, DMODEL, DFF);
        reduce2_kernel<<<M_ROWS, blk, 0, stream>>>(h, yfP, doP, 2048);
    }

    ln_kernel<float, false><<<M_ROWS, blk, 0, stream>>>(h, nullptr, lnf_s, lnf_b,
                                                        (float*)d_out);
}

// Round 6
// 1451.352 us; speedup vs baseline: 1.4234x; 1.0098x over previous
//
#include <hip/hip_runtime.h>
#include <hip/hip_bf16.h>
#include <math.h>

typedef __hip_bfloat16 bf16;
typedef __attribute__((ext_vector_type(8))) short short8;
typedef __attribute__((ext_vector_type(4))) float f32x4;

#define S_LEN 1024
#define BATCH 4
#define M_ROWS 4096
#define DMODEL 1024
#define DFF 4096
#define NHEAD 8
#define DHEAD 128
#define WIN 100
#define LFWD 20

#define SCHED0 __builtin_amdgcn_sched_barrier(0)

__device__ __forceinline__ void gl_lds16(const void* g, void* l) {
    __builtin_amdgcn_global_load_lds(
        (const __attribute__((address_space(1))) void*)g,
        (__attribute__((address_space(3))) void*)l, 16, 0, 0);
}

__device__ __forceinline__ float bf2f(unsigned short u) {
    return __uint_as_float(((unsigned)u) << 16);
}

// XCD-aware bijective swizzle (nb is always a multiple of 8 here):
__device__ __forceinline__ int xcd_swz(int flat, int nb) {
    return (flat & 7) * (nb >> 3) + (flat >> 3);
}

// ---------------- MFMA GEMM (no split): C = act(A @ Bt^T + bias) ----------------
// depth-3 pipeline, counted vmcnt (never drains to 0 in steady state).
template<typename TC>
__global__ __launch_bounds__(256)
void mfma_gemm(const bf16* __restrict__ A, const bf16* __restrict__ Bt,
               const float* __restrict__ bias, TC* __restrict__ C,
               int M, int N, int K, int act)
{
    __shared__ bf16 As[3][128 * 32];
    __shared__ bf16 Bs[3][128 * 32];
    const int gx = gridDim.x;
    const int nb = gx * gridDim.y;
    const int swz = xcd_swz(blockIdx.x + gx * blockIdx.y, nb);
    const int bn = (swz % gx) * 128;
    const int bm = (swz / gx) * 128;
    const int tid = threadIdx.x;
    const int w = tid >> 6, lane = tid & 63;
    const int wm = (w & 1) * 64, wn = (w >> 1) * 64;

    const int srow = w * 32 + (lane >> 2);
    const int selem = (lane & 3) * 8;
    const bf16* ga0 = A + (size_t)(bm + srow) * K + selem;
    const bf16* ga1 = ga0 + (size_t)16 * K;
    const bf16* gb0 = Bt + (size_t)(bn + srow) * K + selem;
    const bf16* gb1 = gb0 + (size_t)16 * K;
    const int l0 = (w * 32) * 32;
    const int l1 = (w * 32 + 16) * 32;

    f32x4 acc[4][4] = {};
    const int koff = (lane >> 4) * 8;
    const int fr = lane & 15;

    auto STAGE = [&](int t, int buf) {
        gl_lds16(ga0 + t * 32, As[buf] + l0);
        gl_lds16(ga1 + t * 32, As[buf] + l1);
        gl_lds16(gb0 + t * 32, Bs[buf] + l0);
        gl_lds16(gb1 + t * 32, Bs[buf] + l1);
    };

    const int nk = K >> 5;
    STAGE(0, 0);
    if (nk > 1) STAGE(1, 1);
    if (nk > 2) STAGE(2, 2);

    for (int t = 0; t < nk; ++t) {
        const int ahead = nk - 1 - t;
        if (ahead >= 2)      asm volatile("s_waitcnt vmcnt(8)" ::: "memory");
        else if (ahead == 1) asm volatile("s_waitcnt vmcnt(4)" ::: "memory");
        else                 asm volatile("s_waitcnt vmcnt(0)" ::: "memory");
        SCHED0;
        __builtin_amdgcn_s_barrier();
        SCHED0;
        const bf16* Ac = As[t % 3];
        const bf16* Bc = Bs[t % 3];
        short8 af[4], bfr[4];
#pragma unroll
        for (int i = 0; i < 4; ++i)
            af[i] = *(const short8*)(Ac + (wm + i * 16 + fr) * 32 + koff);
#pragma unroll
        for (int j = 0; j < 4; ++j)
            bfr[j] = *(const short8*)(Bc + (wn + j * 16 + fr) * 32 + koff);
#pragma unroll
        for (int i = 0; i < 4; ++i)
#pragma unroll
            for (int j = 0; j < 4; ++j)
                acc[i][j] = __builtin_amdgcn_mfma_f32_16x16x32_bf16(
                    af[i], bfr[j], acc[i][j], 0, 0, 0);
        asm volatile("s_waitcnt lgkmcnt(0)" ::: "memory");
        SCHED0;
        __builtin_amdgcn_s_barrier();
        SCHED0;
        if (t + 3 < nk) STAGE(t + 3, t % 3);
    }

    const int cq = lane >> 4, cn = lane & 15;
#pragma unroll
    for (int i = 0; i < 4; ++i) {
#pragma unroll
        for (int r = 0; r < 4; ++r) {
            int row = bm + wm + i * 16 + cq * 4 + r;
#pragma unroll
            for (int j = 0; j < 4; ++j) {
                int col = bn + wn + j * 16 + cn;
                float v = acc[i][j][r] + bias[col];
                if (act) v = v / (1.0f + __expf(-v));   // silu
                C[(size_t)row * N + col] = (TC)v;
            }
        }
    }
}

// ---------- MFMA GEMM split-K=2: z=0 -> C=acc+bias(+resid), z=1 -> P=acc ----------
__global__ __launch_bounds__(256)
void mfma_gemm_sk(const bf16* __restrict__ A, const bf16* __restrict__ Bt,
                  const float* __restrict__ bias, float* __restrict__ C,
                  const float* __restrict__ resid,
                  float* __restrict__ P0, float* __restrict__ P1, int prows0,
                  int M, int N, int K)
{
    __shared__ bf16 As[3][128 * 32];
    __shared__ bf16 Bs[3][128 * 32];
    const int gx = gridDim.x, gy = gridDim.y;
    const int nb = gx * gy * 2;
    const int swz = xcd_swz(blockIdx.x + gx * (blockIdx.y + gy * blockIdx.z), nb);
    const int bn = (swz % gx) * 128;
    const int bm = ((swz / gx) % gy) * 128;
    const int z  = swz / (gx * gy);
    const int khalf = K >> 1;
    const int kstart = z * khalf;
    const int tid = threadIdx.x;
    const int w = tid >> 6, lane = tid & 63;
    const int wm = (w & 1) * 64, wn = (w >> 1) * 64;

    const int srow = w * 32 + (lane >> 2);
    const int selem = (lane & 3) * 8;
    const bf16* ga0 = A + (size_t)(bm + srow) * K + kstart + selem;
    const bf16* ga1 = ga0 + (size_t)16 * K;
    const bf16* gb0 = Bt + (size_t)(bn + srow) * K + kstart + selem;
    const bf16* gb1 = gb0 + (size_t)16 * K;
    const int l0 = (w * 32) * 32;
    const int l1 = (w * 32 + 16) * 32;

    f32x4 acc[4][4] = {};
    const int koff = (lane >> 4) * 8;
    const int fr = lane & 15;

    auto STAGE = [&](int t, int buf) {
        gl_lds16(ga0 + t * 32, As[buf] + l0);
        gl_lds16(ga1 + t * 32, As[buf] + l1);
        gl_lds16(gb0 + t * 32, Bs[buf] + l0);
        gl_lds16(gb1 + t * 32, Bs[buf] + l1);
    };

    const int nk = khalf >> 5;
    STAGE(0, 0);
    if (nk > 1) STAGE(1, 1);
    if (nk > 2) STAGE(2, 2);

    for (int t = 0; t < nk; ++t) {
        const int ahead = nk - 1 - t;
        if (ahead >= 2)      asm volatile("s_waitcnt vmcnt(8)" ::: "memory");
        else if (ahead == 1) asm volatile("s_waitcnt vmcnt(4)" ::: "memory");
        else                 asm volatile("s_waitcnt vmcnt(0)" ::: "memory");
        SCHED0;
        __builtin_amdgcn_s_barrier();
        SCHED0;
        const bf16* Ac = As[t % 3];
        const bf16* Bc = Bs[t % 3];
        short8 af[4], bfr[4];
#pragma unroll
        for (int i = 0; i < 4; ++i)
            af[i] = *(const short8*)(Ac + (wm + i * 16 + fr) * 32 + koff);
#pragma unroll
        for (int j = 0; j < 4; ++j)
            bfr[j] = *(const short8*)(Bc + (wn + j * 16 + fr) * 32 + koff);
#pragma unroll
        for (int i = 0; i < 4; ++i)
#pragma unroll
            for (int j = 0; j < 4; ++j)
                acc[i][j] = __builtin_amdgcn_mfma_f32_16x16x32_bf16(
                    af[i], bfr[j], acc[i][j], 0, 0, 0);
        asm volatile("s_waitcnt lgkmcnt(0)" ::: "memory");
        SCHED0;
        __builtin_amdgcn_s_barrier();
        SCHED0;
        if (t + 3 < nk) STAGE(t + 3, t % 3);
    }

    const int cq = lane >> 4, cn = lane & 15;
#pragma unroll
    for (int i = 0; i < 4; ++i) {
#pragma unroll
        for (int r = 0; r < 4; ++r) {
            int row = bm + wm + i * 16 + cq * 4 + r;
#pragma unroll
            for (int j = 0; j < 4; ++j) {
                int col = bn + wn + j * 16 + cn;
                float v = acc[i][j][r];
                if (z == 0) {
                    v += bias[col];
                    if (resid) v += resid[(size_t)row * N + col];
                    C[(size_t)row * N + col] = v;
                } else {
                    float* P = (row < prows0) ? (P0 + (size_t)row * N + col)
                                              : (P1 + (size_t)(row - prows0) * N + col);
                    *P = v;
                }
            }
        }
    }
}

// -------- transpose+cast: W (K x N fp32, row stride ld) -> Wt (N x K bf16) --------
__global__ void transpose_kernel(const float* __restrict__ W, bf16* __restrict__ Wt,
                                 int K, int N, int ld)
{
    __shared__ float t[32][33];
    const int n0 = blockIdx.x * 32, k0 = blockIdx.y * 32;
    const int tx = threadIdx.x & 31, ty = threadIdx.x >> 5;
#pragma unroll
    for (int i = 0; i < 32; i += 8)
        t[ty + i][tx] = W[(size_t)(k0 + ty + i) * ld + n0 + tx];
    __syncthreads();
#pragma unroll
    for (int i = 0; i < 32; i += 8)
        Wt[(size_t)(n0 + ty + i) * K + k0 + tx] = (bf16)t[tx][ty + i];
}

// -------- v (qkv col 2048+) -> vt[b][h][d][s] bf16 --------
__global__ void vtrans_kernel(const bf16* __restrict__ qkv, bf16* __restrict__ vt)
{
    __shared__ bf16 t[32][33];
    const int bh = blockIdx.z;
    const int s0 = blockIdx.x * 32, d0 = blockIdx.y * 32;
    const int b = bh >> 3, h = bh & 7;
    const int tx = threadIdx.x & 31, ty = threadIdx.x >> 5;
#pragma unroll
    for (int i = 0; i < 32; i += 8)
        t[ty + i][tx] = qkv[(size_t)(b * S_LEN + s0 + ty + i) * 3072 + 2048
                            + h * DHEAD + d0 + tx];
    __syncthreads();
#pragma unroll
    for (int i = 0; i < 32; i += 8)
        vt[(size_t)(bh * DHEAD + d0 + ty + i) * 1024 + s0 + tx] = t[tx][ty + i];
}

// ---------------- fp32 -> bf16 convert ----------------
__global__ void cvt_kernel(const float* __restrict__ s, bf16* __restrict__ d)
{
    size_t i = ((size_t)blockIdx.x * 256 + threadIdx.x) * 4;
    float4 v = *(const float4*)(s + i);
    d[i] = (bf16)v.x; d[i + 1] = (bf16)v.y; d[i + 2] = (bf16)v.z; d[i + 3] = (bf16)v.w;
}

// ---------------- concat 3 bias vectors of 1024 fp32 ----------------
__global__ void concat3_kernel(const float* __restrict__ a, const float* __restrict__ b,
                               const float* __restrict__ c, float* __restrict__ o)
{
    int i = blockIdx.x * 256 + threadIdx.x;
    o[i] = (i < 1024) ? a[i] : (i < 2048 ? b[i - 1024] : c[i - 2048]);
}

// ---------------- h = pad ? 0 : h + P ----------------
__global__ void pad_red_kernel(float* __restrict__ h, const float* __restrict__ P,
                               const int* __restrict__ xlen)
{
    int row = blockIdx.x;
    int b = row >> 10, s = row & 1023;
    int len = xlen[b] >> 2;
    size_t off = (size_t)row * DMODEL;
    if (s >= len) {
        for (int d = threadIdx.x; d < DMODEL; d += 256) h[off + d] = 0.0f;
    } else {
        for (int d = threadIdx.x; d < DMODEL; d += 256) h[off + d] += P[off + d];
    }
}

// ---------------- h += P (split P0/P1) ----------------
__global__ void reduce2_kernel(float* __restrict__ h, const float* __restrict__ P0,
                               const float* __restrict__ P1, int prows0)
{
    int row = blockIdx.x;
    const float* P = (row < prows0) ? (P0 + (size_t)row * DMODEL)
                                    : (P1 + (size_t)(row - prows0) * DMODEL);
    size_t off = (size_t)row * DMODEL;
#pragma unroll
    for (int t = 0; t < 4; ++t) {
        int d = threadIdx.x + 256 * t;
        h[off + d] += P[d];
    }
}

// ---------------- LayerNorm (row of 1024) ----------------
template<typename TO, bool RED>
__global__ void ln_kernel(float* __restrict__ x, const float* __restrict__ P0,
                          const float* __restrict__ sc, const float* __restrict__ bi,
                          TO* __restrict__ y)
{
    int row = blockIdx.x;
    float* xr = x + (size_t)row * DMODEL;
    const float* pr = RED ? (P0 + (size_t)row * DMODEL) : nullptr;
    float vals[4];
    float lsum = 0.0f, lsq = 0.0f;
#pragma unroll
    for (int t = 0; t < 4; ++t) {
        int d = threadIdx.x + 256 * t;
        float v = xr[d];
        if (RED) { v += pr[d]; xr[d] = v; }
        vals[t] = v; lsum += v; lsq += v * v;
    }
    for (int o = 32; o > 0; o >>= 1) {
        lsum += __shfl_down(lsum, o, 64);
        lsq  += __shfl_down(lsq,  o, 64);
    }
    __shared__ float s1[4], s2[4];
    int wv = threadIdx.x >> 6, ln = threadIdx.x & 63;
    if (ln == 0) { s1[wv] = lsum; s2[wv] = lsq; }
    __syncthreads();
    if (threadIdx.x == 0) {
        float a = s1[0] + s1[1] + s1[2] + s1[3];
        float b = s2[0] + s2[1] + s2[2] + s2[3];
        float mu = a * (1.0f / DMODEL);
        float var = b * (1.0f / DMODEL) - mu * mu;
        s1[0] = mu;
        s2[0] = rsqrtf(fmaxf(var, 0.0f) + 1e-5f);
    }
    __syncthreads();
    float mu = s1[0], inv = s2[0];
#pragma unroll
    for (int t = 0; t < 4; ++t) {
        int d = threadIdx.x + 256 * t;
        y[(size_t)row * DMODEL + d] = (TO)((vals[t] - mu) * inv * sc[d] + bi[d]);
    }
}

// ---------------- RoPE (in-place, bf16, strided) ----------------
__global__ void rope_kernel(bf16* __restrict__ q, bf16* __restrict__ k, int stride)
{
    size_t idx = (size_t)blockIdx.x * 256 + threadIdx.x;
    int d = idx & 63;
    size_t rest = idx >> 6;
    int hh = rest & 7;
    int s = (rest >> 3) & 1023;
    size_t base = (rest >> 3) * stride + (size_t)hh * DHEAD;
    float inv = exp2f((float)d * -0.20762050593045235f);
    float ang = (float)s * inv;
    float c, si;
    __sincosf(ang, &si, &c);
    {
        float x1 = (float)q[base + d], x2 = (float)q[base + 64 + d];
        q[base + d]      = (bf16)(x1 * c - x2 * si);
        q[base + 64 + d] = (bf16)(x1 * si + x2 * c);
    }
    {
        float x1 = (float)k[base + d], x2 = (float)k[base + 64 + d];
        k[base + d]      = (bf16)(x1 * c - x2 * si);
        k[base + 64 + d] = (bf16)(x1 * si + x2 * c);
    }
}

// ------- mean of v over s, two-stage -------
__global__ void vmean_part(const bf16* __restrict__ v, float* __restrict__ part,
                           int stride)
{
    int g = blockIdx.x;
    int chunk = g & 31;
    int bh = g >> 5;
    int b = bh >> 3, hh = bh & 7;
    int d = threadIdx.x;
    const bf16* base = v + ((size_t)(b * S_LEN + chunk * 32)) * stride
                         + hh * DHEAD + d;
    float acc = 0.0f;
#pragma unroll 4
    for (int s = 0; s < 32; ++s)
        acc += (float)base[(size_t)s * stride];
    part[((size_t)bh * 32 + chunk) * DHEAD + d] = acc;
}

__global__ void vmean_fin(const float* __restrict__ part, float* __restrict__ vmean)
{
    int bh = blockIdx.x;
    int d = threadIdx.x;
    float acc = 0.0f;
#pragma unroll
    for (int c = 0; c < 32; ++c)
        acc += part[((size_t)bh * 32 + c) * DHEAD + d];
    vmean[(size_t)bh * DHEAD + d] = acc * (1.0f / S_LEN);
}

// ============== MFMA windowed attention ==============
__global__ __launch_bounds__(128)
void attn_mfma(const bf16* __restrict__ qkv, const bf16* __restrict__ vt_g,
               const float* __restrict__ vmean, const int* __restrict__ xlen,
               bf16* __restrict__ ctx)
{
    __shared__ bf16 KV[2][64 * 128];     // 2 x 16 KB
    __shared__ bf16 P[2][16 * 192];      // per-wave P, 12 KB

    const int qt = blockIdx.x;           // 32 tiles of 32 queries
    const int bh = blockIdx.y;           // b*8+h
    const int b = bh >> 3, h = bh & 7;
    const int tid = threadIdx.x;
    const int w = tid >> 6, l = tid & 63;
    const int qlo = qt * 32;
    const int len = xlen[b] >> 2;

    int s0 = qlo - 128; if (s0 < 0) s0 = 0;
    const int jmax = qlo + 51;
    int k0t[3]; int nt = 0;
#pragma unroll
    for (int t = 0; t < 3; ++t) {
        int k0 = s0 + t * 64;
        if (k0 <= jmax && k0 < len) { k0t[nt] = k0; ++nt; }
    }

    const bf16* qbase = qkv + (size_t)(b * S_LEN) * 3072 + h * DHEAD;
    const bf16* kbase = qbase + DMODEL;

    short8 qa[4];
    {
        const bf16* qr = qbase + (size_t)(qlo + w * 16 + (l & 15)) * 3072 + (l >> 4) * 8;
#pragma unroll
        for (int kk = 0; kk < 4; ++kk)
            qa[kk] = *(const short8*)(qr + kk * 32);
    }

    auto stageK = [&](int k0, int buf) {
#pragma unroll
        for (int c = 0; c < 8; ++c) {
            int rl = w * 32 + c * 4 + (l >> 4);
            int sr = k0 + rl; if (sr > S_LEN - 1) sr = S_LEN - 1;
            int sc = ((l & 15) * 8) ^ ((rl & 7) << 3);
            gl_lds16(kbase + (size_t)sr * 3072 + sc,
                     &KV[buf][(w * 32 + c * 4) * 128]);
        }
    };
    auto stageV = [&](int k0, int buf) {
#pragma unroll
        for (int c = 0; c < 8; ++c) {
            int d = w * 64 + c * 8 + (l >> 3);
            int js = ((l & 7) * 8) ^ ((d & 7) << 3);
            int s = k0 + js; if (s > S_LEN - 8) s = S_LEN - 8;
            gl_lds16(vt_g + (size_t)(bh * 128 + d) * 1024 + s,
                     &KV[buf][(w * 64 + c * 8) * 64]);
        }
    };

    f32x4 sf[3][4] = {};

    auto sphase = [&](int t, int buf) {
#pragma unroll
        for (int jb = 0; jb < 4; ++jb) {
            int row = jb * 16 + (l & 15);
#pragma unroll
            for (int kk = 0; kk < 4; ++kk) {
                int kel = (kk * 32 + (l >> 4) * 8) ^ ((row & 7) << 3);
                short8 kf = *(const short8*)(&KV[buf][row * 128 + kel]);
                sf[t][jb] = __builtin_amdgcn_mfma_f32_16x16x32_bf16(
                    qa[kk], kf, sf[t][jb], 0, 0, 0);
            }
        }
    };

    if (nt > 0) stageK(k0t[0], 0);
    __syncthreads();
    if (nt > 1) stageK(k0t[1], 1);
    if (nt > 0) sphase(0, 0);
    __syncthreads();
    if (nt > 2) stageK(k0t[2], 0);
    if (nt > 1) sphase(1, 1);
    __syncthreads();
    if (nt > 2) sphase(2, 0);
    if (nt > 0) stageV(k0t[0], 1);

    const float scale = 0.088388347648318447f;  // 1/sqrt(128)
    float mr[4] = {-1e30f, -1e30f, -1e30f, -1e30f};
#pragma unroll
    for (int t = 0; t < 3; ++t) if (t < nt) {
#pragma unroll
        for (int jb = 0; jb < 4; ++jb) {
            int j = k0t[t] + jb * 16 + (l & 15);
            bool jok = (j < len);
#pragma unroll
            for (int r = 0; r < 4; ++r) {
                int i = qlo + w * 16 + ((l >> 4) << 2) + r;
                float v = sf[t][jb][r] * scale;
                bool ok = jok && (j - i <= LFWD) && (i - j < WIN);
                v = ok ? v : -1e30f;
                sf[t][jb][r] = v;
                mr[r] = fmaxf(mr[r], v);
            }
        }
    }
#pragma unroll
    for (int o = 1; o <= 8; o <<= 1)
#pragma unroll
        for (int r = 0; r < 4; ++r)
            mr[r] = fmaxf(mr[r], __shfl_xor(mr[r], o, 64));

    float lr[4] = {0.0f, 0.0f, 0.0f, 0.0f};
#pragma unroll
    for (int t = 0; t < 3; ++t) if (t < nt) {
#pragma unroll
        for (int jb = 0; jb < 4; ++jb) {
#pragma unroll
            for (int r = 0; r < 4; ++r) {
                int q = ((l >> 4) << 2) + r;
                int jrel = t * 64 + jb * 16 + (l & 15);
                float e = __expf(sf[t][jb][r] - mr[r]);
                lr[r] += e;
                P[w][q * 192 + (jrel ^ ((q & 7) << 3))] = (bf16)e;
            }
        }
    }
#pragma unroll
    for (int o = 1; o <= 8; o <<= 1)
#pragma unroll
        for (int r = 0; r < 4; ++r)
            lr[r] += __shfl_xor(lr[r], o, 64);
    float inv[4];
#pragma unroll
    for (int r = 0; r < 4; ++r) inv[r] = 1.0f / fmaxf(lr[r], 1e-30f);

    __syncthreads();

    f32x4 acc[8] = {};
    auto pv = [&](int ti, int buf) {
#pragma unroll
        for (int s32 = 0; s32 < 2; ++s32) {
            int q = l & 15;
            int jr8 = ti * 64 + s32 * 32 + (l >> 4) * 8;
            short8 pa = *(const short8*)(&P[w][q * 192 + (jr8 ^ ((q & 7) << 3))]);
#pragma unroll
            for (int db = 0; db < 8; ++db) {
                int d = db * 16 + (l & 15);
                int je = (s32 * 32 + (l >> 4) * 8) ^ ((d & 7) << 3);
                short8 vf = *(const short8*)(&KV[buf][d * 64 + je]);
                acc[db] = __builtin_amdgcn_mfma_f32_16x16x32_bf16(
                    pa, vf, acc[db], 0, 0, 0);
            }
        }
    };

    if (nt > 1) stageV(k0t[1], 0);
    if (nt > 0) pv(0, 1);
    __syncthreads();
    if (nt > 2) stageV(k0t[2], 1);
    if (nt > 1) pv(1, 0);
    __syncthreads();
    if (nt > 2) pv(2, 1);

    const float* vm = vmean + (size_t)bh * DHEAD;
    float vmr[8];
#pragma unroll
    for (int db = 0; db < 8; ++db) vmr[db] = vm[db * 16 + (l & 15)];
#pragma unroll
    for (int r = 0; r < 4; ++r) {
        int i = qlo + w * 16 + ((l >> 4) << 2) + r;
        bf16* crow = ctx + (size_t)(b * S_LEN + i) * DMODEL + h * DHEAD;
        bool em = mr[r] < -1e29f;
        float iv = inv[r];
#pragma unroll
        for (int db = 0; db < 8; ++db) {
            float v = em ? vmr[db] : acc[db][r] * iv;
            crow[db * 16 + (l & 15)] = (bf16)v;
        }
    }
}

extern "C" void kernel_launch(void* const* d_in, const int* in_sizes, int n_in,
                              void* d_out, int out_size, void* d_ws, size_t ws_size,
                              hipStream_t stream)
{
    const float* x      = (const float*)d_in[0];
    const int*   xlen   = (const int*)d_in[1];
    const float* Wp     = (const float*)d_in[2];
    const float* bp     = (const float*)d_in[3];
    const float* ln1_s  = (const float*)d_in[4];
    const float* ln1_b  = (const float*)d_in[5];
    const float* Wq     = (const float*)d_in[6];
    const float* bq     = (const float*)d_in[7];
    const float* Wk     = (const float*)d_in[8];
    const float* bk     = (const float*)d_in[9];
    const float* Wv     = (const float*)d_in[10];
    const float* bv     = (const float*)d_in[11];
    const float* Wo     = (const float*)d_in[12];
    const float* bo     = (const float*)d_in[13];
    const float* ln2_s  = (const float*)d_in[14];
    const float* ln2_b  = (const float*)d_in[15];
    const float* W1     = (const float*)d_in[16];
    const float* b1     = (const float*)d_in[17];
    const float* W2     = (const float*)d_in[18];
    const float* b2     = (const float*)d_in[19];
    const float* lnf_s  = (const float*)d_in[20];
    const float* lnf_b  = (const float*)d_in[21];
    (void)in_sizes; (void)n_in; (void)out_size; (void)ws_size;

    const size_t MD = (size_t)M_ROWS * DMODEL;
    float* h     = (float*)d_ws;                          // [0,16) MB
    bf16*  y     = (bf16*)(h + MD);                       // [16,24) MB
    float* yfP   = (float*)(h + MD);
    bf16*  U     = y + MD;                                // [24,56) MB union
    bf16*  xb    = U;
    bf16*  qkv   = U;
    bf16*  mid   = U;
    float* UfP   = (float*)U;
    float* UfP2  = (float*)(U + 8 * 1024 * 1024);
    float* vmean = (float*)(U + 16 * 1024 * 1024);
    float* bqkv  = vmean + BATCH * NHEAD * DHEAD;
    bf16*  wt    = (bf16*)d_out;                          // [0,8) MB of d_out
    float* doP   = (float*)((char*)d_out + 8 * 1024 * 1024);
    float* vpart = doP;
    bf16*  vt_g  = (bf16*)d_out;                          // V^T, 8 MB (wt dead)
    const int QS = 3 * DMODEL;

    dim3 blk(256);
    dim3 gSK(DMODEL / 128, M_ROWS / 128, 2);

    cvt_kernel<<<(2 * MD) / (256 * 4), blk, 0, stream>>>(x, xb);
    transpose_kernel<<<dim3(DMODEL / 32, 2048 / 32), blk, 0, stream>>>(Wp, wt, 2048, DMODEL, DMODEL);
    mfma_gemm_sk<<<gSK, blk, 0, stream>>>(xb, wt, bp, h, nullptr,
                                          UfP2, nullptr, M_ROWS, M_ROWS, DMODEL, 2048);
    pad_red_kernel<<<M_ROWS, blk, 0, stream>>>(h, UfP2, xlen);

    for (int l = 0; l < 4; ++l) {
        const size_t wD  = (size_t)l * DMODEL * DMODEL;
        const size_t wF  = (size_t)l * DMODEL * DFF;
        const size_t wF2 = (size_t)l * DFF * DMODEL;
        const size_t vD  = (size_t)l * DMODEL;
        const size_t vF  = (size_t)l * DFF;

        ln_kernel<bf16, false><<<M_ROWS, blk, 0, stream>>>(h, nullptr,
                                                           ln1_s + vD, ln1_b + vD, y);

        transpose_kernel<<<dim3(32, 32), blk, 0, stream>>>(Wq + wD, wt, DMODEL, DMODEL, DMODEL);
        transpose_kernel<<<dim3(32, 32), blk, 0, stream>>>(Wk + wD, wt + MD / 4, DMODEL, DMODEL, DMODEL);
        transpose_kernel<<<dim3(32, 32), blk, 0, stream>>>(Wv + wD, wt + MD / 2, DMODEL, DMODEL, DMODEL);
        concat3_kernel<<<12, blk, 0, stream>>>(bq + vD, bk + vD, bv + vD, bqkv);
        mfma_gemm<bf16><<<dim3(3 * DMODEL / 128, M_ROWS / 128), blk, 0, stream>>>(
            y, wt, bqkv, qkv, M_ROWS, 3 * DMODEL, DMODEL, 0);

        bf16* qb = qkv;
        bf16* kb = qkv + DMODEL;
        bf16* vb = qkv + 2 * DMODEL;
        rope_kernel<<<(M_ROWS * NHEAD * 64) / 256, blk, 0, stream>>>(qb, kb, QS);
        vtrans_kernel<<<dim3(32, 4, 32), blk, 0, stream>>>(qkv, vt_g);
        vmean_part<<<BATCH * NHEAD * 32, dim3(DHEAD), 0, stream>>>(vb, vpart, QS);
        vmean_fin<<<BATCH * NHEAD, dim3(DHEAD), 0, stream>>>(vpart, vmean);
        attn_mfma<<<dim3(32, 32), dim3(128), 0, stream>>>(qkv, vt_g, vmean, xlen, y);

        transpose_kernel<<<dim3(32, 32), blk, 0, stream>>>(Wo + wD, wt, DMODEL, DMODEL, DMODEL);
        mfma_gemm_sk<<<gSK, blk, 0, stream>>>(y, wt, bo + vD, h, h,
                                              UfP, nullptr, M_ROWS, M_ROWS, DMODEL, 1024);

        ln_kernel<bf16, true><<<M_ROWS, blk, 0, stream>>>(h, UfP,
                                                          ln2_s + vD, ln2_b + vD, y);

        transpose_kernel<<<dim3(DFF / 32, DMODEL / 32), blk, 0, stream>>>(
            W1 + wF, wt, DMODEL, DFF, DFF);
        mfma_gemm<bf16><<<dim3(DFF / 128, M_ROWS / 128), blk, 0, stream>>>(
            y, wt, b1 + vF, mid, M_ROWS, DFF, DMODEL, 1);

        transpose_kernel<<<dim3(DMODEL / 32, DFF / 32), blk, 0, stream>>>(
            W2 + wF2, wt, DFF, DMODEL, DMODEL);
        mfma_gemm_sk<<<gSK, blk, 0, stream>>>(mid, wt, b2 + vD, h, h,
                                              yfP, doP, 2048, M_ROWS, DMODEL, DFF);
        reduce2_kernel<<<M_ROWS, blk, 0, stream>>>(h, yfP, doP, 2048);
    }

    ln_kernel<float, false><<<M_ROWS, blk, 0, stream>>>(h, nullptr, lnf_s, lnf_b,
                                                        (float*)d_out);
}